// Round 1
// baseline (10542.513 us; speedup 1.0000x reference)
//
#include <hip/hip_runtime.h>
#include <hip/hip_bf16.h>
#include <type_traits>

typedef __hip_bfloat16 bf16;

#define N_DET 16384
#define DIN   256
#define DD    1024
#define KSLOT 64
#define HH    2048
#define TD    3072

__device__ __forceinline__ float b2f(bf16 x){ return __bfloat162float(x); }
__device__ __forceinline__ bf16  f2b(float x){ return __float2bfloat16(x); }

// ---------------- big GEMM: C[M,Ncol] = A[M,Kd] @ B[Kd,Ncol] + bias ----------------
// BM=BN=128, BK=16, 256 threads, 8x8 per thread.
template<typename TA, typename TO>
__global__ __launch_bounds__(256) void gemm_big(const TA* __restrict__ A, int lda,
    const float* __restrict__ B, int ldb, const float* __restrict__ bias,
    TO* __restrict__ C, int Kd)
{
  __shared__ float As[16][132];
  __shared__ float Bs[16][132];
  const int tx = threadIdx.x & 15, ty = threadIdx.x >> 4;
  const int bm = blockIdx.y * 128, bn = blockIdx.x * 128;
  float acc[8][8];
#pragma unroll
  for (int i = 0; i < 8; i++)
#pragma unroll
    for (int j = 0; j < 8; j++) acc[i][j] = 0.f;

  for (int k0 = 0; k0 < Kd; k0 += 16) {
    for (int l = threadIdx.x; l < 128*16; l += 256) {
      int r = l >> 4, c = l & 15;
      float v;
      if constexpr (std::is_same<TA, bf16>::value)
        v = b2f(A[(size_t)(bm + r) * lda + k0 + c]);
      else
        v = A[(size_t)(bm + r) * lda + k0 + c];
      As[c][r] = v;
    }
    for (int l = threadIdx.x; l < 16*128; l += 256) {
      int r = l >> 7, c = l & 127;
      Bs[r][c] = B[(size_t)(k0 + r) * ldb + bn + c];
    }
    __syncthreads();
#pragma unroll
    for (int kk = 0; kk < 16; kk++) {
      float a[8], b[8];
#pragma unroll
      for (int i = 0; i < 8; i++) a[i] = As[kk][ty*8 + i];
#pragma unroll
      for (int j = 0; j < 8; j++) b[j] = Bs[kk][tx*8 + j];
#pragma unroll
      for (int i = 0; i < 8; i++)
#pragma unroll
        for (int j = 0; j < 8; j++) acc[i][j] += a[i] * b[j];
    }
    __syncthreads();
  }
#pragma unroll
  for (int i = 0; i < 8; i++) {
    int row = bm + ty*8 + i;
#pragma unroll
    for (int j = 0; j < 8; j++) {
      int col = bn + tx*8 + j;
      float v = acc[i][j] + bias[col];
      if constexpr (std::is_same<TO, bf16>::value)
        C[(size_t)row * ldb + col] = f2b(v);
      else
        C[(size_t)row * ldb + col] = v;
    }
  }
}

// ---------------- layernorm over rows of [R, 1024] ----------------
template<typename TI, typename TO>
__global__ __launch_bounds__(256) void ln_rows(const TI* __restrict__ in, TO* __restrict__ out)
{
  int r = blockIdx.x;
  const TI* p = in + (size_t)r * DD;
  float v[4], s = 0.f, sq = 0.f;
#pragma unroll
  for (int j = 0; j < 4; j++) {
    float x;
    if constexpr (std::is_same<TI, bf16>::value) x = b2f(p[threadIdx.x + j*256]);
    else x = p[threadIdx.x + j*256];
    v[j] = x; s += x; sq += x * x;
  }
  for (int o = 32; o > 0; o >>= 1) { s += __shfl_down(s, o, 64); sq += __shfl_down(sq, o, 64); }
  __shared__ float ls[4], lq[4];
  int w = threadIdx.x >> 6;
  if ((threadIdx.x & 63) == 0) { ls[w] = s; lq[w] = sq; }
  __syncthreads();
  s  = ls[0] + ls[1] + ls[2] + ls[3];
  sq = lq[0] + lq[1] + lq[2] + lq[3];
  float mu = s * (1.f / DD);
  float var = sq * (1.f / DD) - mu * mu;
  float rstd = rsqrtf(var + 1e-5f);
#pragma unroll
  for (int j = 0; j < 4; j++) {
    float o = (v[j] - mu) * rstd;
    if constexpr (std::is_same<TO, bf16>::value) out[(size_t)r*DD + threadIdx.x + j*256] = f2b(o);
    else out[(size_t)r*DD + threadIdx.x + j*256] = o;
  }
}

// ---------------- dots^T[n,s] = k[n]·q[s] * scale, softmax over s, col-sums ----------------
__global__ __launch_bounds__(256) void dots_softmax(const bf16* __restrict__ k,
    const float* __restrict__ q, float* __restrict__ attnT, float* __restrict__ colsum)
{
  __shared__ float qs[64][65];
  __shared__ float ks[64][65];
  __shared__ float cs[64];
  int t = threadIdx.x;
  int n0 = blockIdx.x * 64;
  int r = t >> 2, g = t & 3;
  float acc[16];
#pragma unroll
  for (int i = 0; i < 16; i++) acc[i] = 0.f;

  for (int d0 = 0; d0 < DD; d0 += 64) {
    for (int l = t; l < 4096; l += 256) {
      int a = l >> 6, b = l & 63;
      qs[a][b] = q[(size_t)a * DD + d0 + b];
      ks[a][b] = b2f(k[(size_t)(n0 + a) * DD + d0 + b]);
    }
    __syncthreads();
    for (int dd = 0; dd < 64; dd++) {
      float kv = ks[r][dd];
#pragma unroll
      for (int i = 0; i < 16; i++) acc[i] += kv * qs[g*16 + i][dd];
    }
    __syncthreads();
  }
  float m = -1e30f;
#pragma unroll
  for (int i = 0; i < 16; i++) { acc[i] *= 0.03125f; m = fmaxf(m, acc[i]); }
  m = fmaxf(m, __shfl_xor(m, 1, 64));
  m = fmaxf(m, __shfl_xor(m, 2, 64));
  float ssum = 0.f;
#pragma unroll
  for (int i = 0; i < 16; i++) { acc[i] = expf(acc[i] - m); ssum += acc[i]; }
  ssum += __shfl_xor(ssum, 1, 64);
  ssum += __shfl_xor(ssum, 2, 64);
  float inv = 1.f / ssum;
  if (t < 64) cs[t] = 0.f;
  __syncthreads();
#pragma unroll
  for (int i = 0; i < 16; i++) {
    float a = acc[i] * inv;
    attnT[(size_t)(n0 + r) * 64 + g*16 + i] = a;
    atomicAdd(&cs[g*16 + i], a);
  }
  __syncthreads();
  if (t < 64) atomicAdd(&colsum[t], cs[t]);
}

// ---------------- updates split-K partial: pbuf[kc][s][d] over 1024 rows ----------------
__global__ __launch_bounds__(256) void updates_partial(const float* __restrict__ attnT,
    const bf16* __restrict__ v, float* __restrict__ pbuf)
{
  __shared__ float at[64][65];
  __shared__ float vt[64][65];
  int t = threadIdx.x;
  int dt = blockIdx.x * 64;
  int kc = blockIdx.y;
  int s = t >> 2, g = t & 3;
  float acc[16];
#pragma unroll
  for (int i = 0; i < 16; i++) acc[i] = 0.f;

  for (int n0 = kc * 1024; n0 < kc * 1024 + 1024; n0 += 64) {
    for (int l = t; l < 4096; l += 256) {
      int a = l >> 6, b = l & 63;
      at[a][b] = attnT[(size_t)(n0 + a) * 64 + b];
      vt[a][b] = b2f(v[(size_t)(n0 + a) * DD + dt + b]);
    }
    __syncthreads();
    for (int nr = 0; nr < 64; nr++) {
      float a = at[nr][s];
#pragma unroll
      for (int i = 0; i < 16; i++) acc[i] += a * vt[nr][g*16 + i];
    }
    __syncthreads();
  }
#pragma unroll
  for (int i = 0; i < 16; i++)
    pbuf[((size_t)(kc * 64) + s) * DD + dt + g*16 + i] = acc[i];
}

__global__ __launch_bounds__(256) void updates_reduce(const float* __restrict__ pbuf,
    const float* __restrict__ colsum, float* __restrict__ upd)
{
  int gid = blockIdx.x * 256 + threadIdx.x;   // 65536
  int s = gid >> 10, d = gid & 1023;
  float sum = 0.f;
#pragma unroll
  for (int c = 0; c < 16; c++) sum += pbuf[((size_t)(c * 64) + s) * DD + d];
  upd[(size_t)s * DD + d] = sum / (colsum[s] + 1e-8f);
}

// ---------------- small-M GEMM: C[64,Ncol] = A[64,Kd] @ B (+bias, epilogue) ----------------
// BT=false: B[Kd,Ncol]; BT=true: B[Ncol,Kd] (dot over last dim). EPI: 0 store, 1 relu, 2 +resid
template<bool BT, int EPI>
__global__ __launch_bounds__(256) void gemm_smallM(const float* __restrict__ A, int Kd,
    const float* __restrict__ B, const float* __restrict__ bias,
    float* __restrict__ C, const float* __restrict__ resid, int Ncol)
{
  __shared__ float As[64][65];
  __shared__ float Bs[64][65];
  int t = threadIdx.x;
  int j0 = blockIdx.x * 64;
  int s = t >> 2, g = t & 3;
  float acc[16];
#pragma unroll
  for (int i = 0; i < 16; i++) acc[i] = 0.f;

  for (int d0 = 0; d0 < Kd; d0 += 64) {
    for (int l = t; l < 4096; l += 256) {
      int a = l >> 6, b = l & 63;
      As[a][b] = A[(size_t)a * Kd + d0 + b];
      if (BT) Bs[b][a] = B[(size_t)(j0 + a) * Kd + d0 + b];
      else    Bs[a][b] = B[(size_t)(d0 + a) * Ncol + j0 + b];
    }
    __syncthreads();
    for (int dd = 0; dd < 64; dd++) {
      float a = As[s][dd];
#pragma unroll
      for (int i = 0; i < 16; i++) acc[i] += a * Bs[dd][g*16 + i];
    }
    __syncthreads();
  }
#pragma unroll
  for (int i = 0; i < 16; i++) {
    int j = j0 + g*16 + i;
    float v = acc[i] + bias[j];
    if (EPI == 1) v = fmaxf(v, 0.f);
    if (EPI == 2) v += resid[(size_t)s * Ncol + j];
    C[(size_t)s * Ncol + j] = v;
  }
}

// ---------------- misc elementwise ----------------
__global__ void slots_init_k(const float* __restrict__ mu, const float* __restrict__ noise,
                             float* __restrict__ slots)
{
  int gid = blockIdx.x * 256 + threadIdx.x;  // 65536
  int d = gid & 1023;
  slots[gid] = mu[d] + noise[gid];
}

__global__ void gru_gate(const float* __restrict__ gi, const float* __restrict__ gh,
                         const float* __restrict__ hprev, float* __restrict__ out)
{
  int gid = blockIdx.x * 256 + threadIdx.x;  // 65536
  int s = gid >> 10, d = gid & 1023;
  float ir = gi[(size_t)s*TD + d],        hr = gh[(size_t)s*TD + d];
  float iz = gi[(size_t)s*TD + 1024 + d], hz = gh[(size_t)s*TD + 1024 + d];
  float in_ = gi[(size_t)s*TD + 2048 + d], hn = gh[(size_t)s*TD + 2048 + d];
  float r = 1.f / (1.f + expf(-(ir + hr)));
  float z = 1.f / (1.f + expf(-(iz + hz)));
  float n = tanhf(in_ + r * hn);
  float h = hprev[gid];
  out[gid] = (1.f - z) * n + z * h;
}

__global__ __launch_bounds__(256) void rownorm(const float* __restrict__ in, float* __restrict__ out)
{
  int r = blockIdx.x;
  const float* p = in + (size_t)r * DD;
  float v[4], sq = 0.f;
#pragma unroll
  for (int j = 0; j < 4; j++) { v[j] = p[threadIdx.x + j*256]; sq += v[j]*v[j]; }
  for (int o = 32; o > 0; o >>= 1) sq += __shfl_down(sq, o, 64);
  __shared__ float lq[4];
  int w = threadIdx.x >> 6;
  if ((threadIdx.x & 63) == 0) lq[w] = sq;
  __syncthreads();
  sq = lq[0] + lq[1] + lq[2] + lq[3];
  float sc = 1.f / (sqrtf(sq) + 1e-8f);
#pragma unroll
  for (int j = 0; j < 4; j++) out[(size_t)r*DD + threadIdx.x + j*256] = v[j] * sc;
}

__global__ __launch_bounds__(256) void sim_kernel(const float* __restrict__ an,
    const float* __restrict__ bn, float* __restrict__ simout)
{
  __shared__ float ar[1024];
  int i = blockIdx.x;
  for (int l = threadIdx.x; l < 1024; l += 256) ar[l] = an[(size_t)i * DD + l];
  __syncthreads();
  int j = threadIdx.x >> 2, g = threadIdx.x & 3;
  float sum = 0.f;
  for (int d = g; d < 1024; d += 4) sum += ar[d] * bn[(size_t)j * DD + d];
  sum += __shfl_xor(sum, 1, 64);
  sum += __shfl_xor(sum, 2, 64);
  if (g == 0) simout[i * 64 + j] = sum;
}

__global__ void match_kernel(const float* __restrict__ sim, float* __restrict__ outm)
{
  __shared__ float m[64];
  __shared__ int idx[64];
  __shared__ int order[64];
  __shared__ int used[64];
  int i = threadIdx.x;   // 64 threads
  float best = -1e30f; int bj = 0;
  for (int j = 0; j < 64; j++) {
    float v = sim[i * 64 + j];
    if (v > best) { best = v; bj = j; }
  }
  m[i] = best; idx[i] = bj; used[i] = 0;
  __syncthreads();
  int cnt = 0;
  for (int j = 0; j < 64; j++) {
    float mj = m[j];
    if (mj > best || (mj == best && j < i)) cnt++;
  }
  order[cnt] = i;
  __syncthreads();
  if (i == 0) {
    for (int r = 0; r < 64; r++) {
      int ii = order[r];
      int j = idx[ii];
      bool ok = (!used[j]) && (m[ii] > 0.3f);
      outm[ii] = ok ? (float)j : -1.0f;
      if (ok) used[j] = 1;
    }
  }
}

// ---------------- workspace layout (bytes) ----------------
static constexpr size_t OFF_SH  = 0;                       // 64MB: x_pre; reused: attnT(4MB)@0, pbuf(4MB)@8MB
static constexpr size_t OFF_PB  = (size_t)8 << 20;
static constexpr size_t OFF_X   = 67108864;                // x bf16 32MB
static constexpr size_t OFF_K   = OFF_X   + 33554432;      // k bf16 32MB
static constexpr size_t OFF_V   = OFF_K   + 33554432;      // v bf16 32MB
static constexpr size_t OFF_SL  = OFF_V   + 33554432;
static constexpr size_t OFF_SLP = OFF_SL  + 262144;
static constexpr size_t OFF_PRV = OFF_SLP + 262144;
static constexpr size_t OFF_LN  = OFF_PRV + 262144;
static constexpr size_t OFF_Q   = OFF_LN  + 262144;
static constexpr size_t OFF_UPD = OFF_Q   + 262144;
static constexpr size_t OFF_GI  = OFF_UPD + 262144;
static constexpr size_t OFF_GH  = OFF_GI  + 786432;
static constexpr size_t OFF_HID = OFF_GH  + 786432;
static constexpr size_t OFF_AN  = OFF_HID + 524288;
static constexpr size_t OFF_BN  = OFF_AN  + 262144;
static constexpr size_t OFF_CS  = OFF_BN  + 262144;

extern "C" void kernel_launch(void* const* d_in, const int* in_sizes, int n_in,
                              void* d_out, int out_size, void* d_ws, size_t ws_size,
                              hipStream_t stream)
{
  (void)in_sizes; (void)n_in; (void)out_size; (void)ws_size;
  const float* dets_t   = (const float*)d_in[0];
  const float* dets_t1  = (const float*)d_in[1];
  const float* W_enc    = (const float*)d_in[2];
  const float* b_enc    = (const float*)d_in[3];
  const float* Wq       = (const float*)d_in[4];
  const float* bq       = (const float*)d_in[5];
  const float* Wk       = (const float*)d_in[6];
  const float* bk       = (const float*)d_in[7];
  const float* Wv       = (const float*)d_in[8];
  const float* bv       = (const float*)d_in[9];
  const float* Wi       = (const float*)d_in[10];
  const float* Wh       = (const float*)d_in[11];
  const float* bi       = (const float*)d_in[12];
  const float* bh       = (const float*)d_in[13];
  const float* W1       = (const float*)d_in[14];
  const float* b1       = (const float*)d_in[15];
  const float* W2       = (const float*)d_in[16];
  const float* b2       = (const float*)d_in[17];
  const float* slots_mu = (const float*)d_in[18];
  const float* init_noise = (const float*)d_in[19];

  char* ws = (char*)d_ws;
  float* x_pre  = (float*)(ws + OFF_SH);
  float* attnT  = (float*)(ws + OFF_SH);
  float* pbuf   = (float*)(ws + OFF_PB);
  bf16*  x      = (bf16*)(ws + OFF_X);
  bf16*  kbuf   = (bf16*)(ws + OFF_K);
  bf16*  vbuf   = (bf16*)(ws + OFF_V);
  float* slots  = (float*)(ws + OFF_SL);
  float* slotsp = (float*)(ws + OFF_SLP);
  float* prevs  = (float*)(ws + OFF_PRV);
  float* lnbuf  = (float*)(ws + OFF_LN);
  float* qbuf   = (float*)(ws + OFF_Q);
  float* upd    = (float*)(ws + OFF_UPD);
  float* gi     = (float*)(ws + OFF_GI);
  float* gh     = (float*)(ws + OFF_GH);
  float* hid    = (float*)(ws + OFF_HID);
  float* an     = (float*)(ws + OFF_AN);
  float* bn     = (float*)(ws + OFF_BN);
  float* colsum = (float*)(ws + OFF_CS);

  auto frame = [&](const float* dets, bool first) {
    gemm_big<float, float><<<dim3(8, 128), 256, 0, stream>>>(dets, DIN, W_enc, DD, b_enc, x_pre, DIN);
    ln_rows<float, bf16><<<N_DET, 256, 0, stream>>>(x_pre, x);
    gemm_big<bf16, bf16><<<dim3(8, 128), 256, 0, stream>>>(x, DD, Wk, DD, bk, kbuf, DD);
    gemm_big<bf16, bf16><<<dim3(8, 128), 256, 0, stream>>>(x, DD, Wv, DD, bv, vbuf, DD);
    if (first) slots_init_k<<<256, 256, 0, stream>>>(slots_mu, init_noise, slots);
    for (int it = 0; it < 3; ++it) {
      hipMemcpyAsync(slotsp, slots, 262144, hipMemcpyDeviceToDevice, stream);
      ln_rows<float, float><<<KSLOT, 256, 0, stream>>>(slots, lnbuf);
      gemm_smallM<false, 0><<<16, 256, 0, stream>>>(lnbuf, DD, Wq, bq, qbuf, nullptr, DD);
      hipMemsetAsync(colsum, 0, 256, stream);
      dots_softmax<<<256, 256, 0, stream>>>(kbuf, qbuf, attnT, colsum);
      updates_partial<<<dim3(16, 16), 256, 0, stream>>>(attnT, vbuf, pbuf);
      updates_reduce<<<256, 256, 0, stream>>>(pbuf, colsum, upd);
      gemm_smallM<true, 0><<<48, 256, 0, stream>>>(upd, DD, Wi, bi, gi, nullptr, TD);
      gemm_smallM<true, 0><<<48, 256, 0, stream>>>(slotsp, DD, Wh, bh, gh, nullptr, TD);
      gru_gate<<<256, 256, 0, stream>>>(gi, gh, slotsp, slots);
      ln_rows<float, float><<<KSLOT, 256, 0, stream>>>(slots, lnbuf);
      gemm_smallM<false, 1><<<32, 256, 0, stream>>>(lnbuf, DD, W1, b1, hid, nullptr, HH);
      gemm_smallM<false, 2><<<16, 256, 0, stream>>>(hid, HH, W2, b2, slots, slots, DD);
    }
  };

  frame(dets_t, true);
  hipMemcpyAsync(prevs, slots, 262144, hipMemcpyDeviceToDevice, stream);
  frame(dets_t1, false);

  rownorm<<<KSLOT, 256, 0, stream>>>(prevs, an);
  rownorm<<<KSLOT, 256, 0, stream>>>(slots, bn);
  float* outf = (float*)d_out;
  sim_kernel<<<KSLOT, 256, 0, stream>>>(an, bn, outf + 64);
  match_kernel<<<1, 64, 0, stream>>>(outf + 64, outf);
}

// Round 2
// 7836.658 us; speedup vs baseline: 1.3453x; 1.3453x over previous
//
#include <hip/hip_runtime.h>
#include <hip/hip_bf16.h>
#include <type_traits>

typedef __hip_bfloat16 bf16;
typedef __attribute__((ext_vector_type(8))) short s16x8;   // 8 bf16 (4 VGPRs)
typedef __attribute__((ext_vector_type(4))) float f32x4;

#define N_DET 16384
#define DIN   256
#define DD    1024
#define KSLOT 64
#define HH    2048
#define TD    3072

__device__ __forceinline__ float b2f(bf16 x){ return __bfloat162float(x); }
__device__ __forceinline__ bf16  f2b(float x){ return __float2bfloat16(x); }

__device__ __forceinline__ void gload_lds16(const void* g, void* l) {
  __builtin_amdgcn_global_load_lds(
      (const __attribute__((address_space(1))) unsigned int*)g,
      (__attribute__((address_space(3))) unsigned int*)l, 16, 0, 0);
}

// ---------------- MFMA GEMM: C[M,N] = A[M,K] @ Bt[N,K]^T + bias ----------------
// m97 structure: 128x128 tile, BK=32, 256 thr = 4 waves, each wave 64x64 (4x4 frags 16x16x32)
template<typename TO>
__global__ __launch_bounds__(256) void gemm_mfma_bt(
    const bf16* __restrict__ A, const bf16* __restrict__ Bt,
    const float* __restrict__ bias, TO* __restrict__ C, int M, int N, int K)
{
  __shared__ bf16 As[128*32];
  __shared__ bf16 Bs[128*32];
  const int bm = blockIdx.y * 128, bn = blockIdx.x * 128;
  const int lane = threadIdx.x & 63, wave = threadIdx.x >> 6;
  const int wr = wave >> 1, wc = wave & 1;   // wave's 64x64 sub-tile

  f32x4 acc[4][4];
  const f32x4 zero = {0.f, 0.f, 0.f, 0.f};
#pragma unroll
  for (int m = 0; m < 4; ++m)
#pragma unroll
    for (int n = 0; n < 4; ++n) acc[m][n] = zero;

  for (int k0 = 0; k0 < K; k0 += 32) {
    __syncthreads();   // previous ds_reads done before overwrite
    // stage A tile [128][32] bf16 (8KB): 512 chunks of 16B, 2 per thread
#pragma unroll
    for (int c = 0; c < 2; ++c) {
      int i = wave * 64 + c * 256 + lane;          // chunk id
      int r = i >> 2, q = i & 3;
      gload_lds16(A + (size_t)(bm + r) * K + k0 + q * 8,
                  As + (size_t)(wave * 64 + c * 256) * 8);
    }
#pragma unroll
    for (int c = 0; c < 2; ++c) {
      int i = wave * 64 + c * 256 + lane;
      int r = i >> 2, q = i & 3;
      gload_lds16(Bt + (size_t)(bn + r) * K + k0 + q * 8,
                  Bs + (size_t)(wave * 64 + c * 256) * 8);
    }
    __syncthreads();   // drains vmcnt before barrier (compiler-inserted)

    s16x8 af[4], bfr[4];
#pragma unroll
    for (int m = 0; m < 4; ++m)
      af[m] = *(const s16x8*)&As[(wr * 64 + m * 16 + (lane & 15)) * 32 + (lane >> 4) * 8];
#pragma unroll
    for (int n = 0; n < 4; ++n)
      bfr[n] = *(const s16x8*)&Bs[(wc * 64 + n * 16 + (lane & 15)) * 32 + (lane >> 4) * 8];
#pragma unroll
    for (int m = 0; m < 4; ++m)
#pragma unroll
      for (int n = 0; n < 4; ++n)
        acc[m][n] = __builtin_amdgcn_mfma_f32_16x16x32_bf16(af[m], bfr[n], acc[m][n], 0, 0, 0);
  }

  // C/D layout: col = lane&15, row = (lane>>4)*4 + j   [measured m89/m91]
#pragma unroll
  for (int m = 0; m < 4; ++m)
#pragma unroll
    for (int n = 0; n < 4; ++n) {
      int col = bn + wc * 64 + n * 16 + (lane & 15);
      float bv = bias[col];
#pragma unroll
      for (int j = 0; j < 4; ++j) {
        int row = bm + wr * 64 + m * 16 + (lane >> 4) * 4 + j;
        float v = acc[m][n][j] + bv;
        if constexpr (std::is_same<TO, bf16>::value)
          C[(size_t)row * N + col] = f2b(v);
        else
          C[(size_t)row * N + col] = v;
      }
    }
}

// ---------------- weight transpose+convert: W[K][N] f32 -> Wt[N][K] bf16 ----------------
__global__ __launch_bounds__(256) void transpose_w(const float* __restrict__ W,
                                                   bf16* __restrict__ Wt, int K, int N)
{
  __shared__ float t[32][33];
  int n0 = blockIdx.x * 32, k0 = blockIdx.y * 32;
  int tx = threadIdx.x & 31, ty = threadIdx.x >> 5;
  for (int r = ty; r < 32; r += 8)
    t[r][tx] = W[(size_t)(k0 + r) * N + n0 + tx];
  __syncthreads();
  for (int r = ty; r < 32; r += 8)
    Wt[(size_t)(n0 + r) * K + k0 + tx] = f2b(t[tx][r]);
}

__global__ void f32_to_bf16_v(const float* __restrict__ in, bf16* __restrict__ out, int n)
{
  int i = (blockIdx.x * 256 + threadIdx.x) * 4;
  if (i < n) {
    float4 v = *(const float4*)(in + i);
    bf16 o[4] = {f2b(v.x), f2b(v.y), f2b(v.z), f2b(v.w)};
    *(ushort4*)(out + i) = *(const ushort4*)o;
  }
}

// ---------------- layernorm over rows of [R, 1024] ----------------
template<typename TI, typename TO>
__global__ __launch_bounds__(256) void ln_rows(const TI* __restrict__ in, TO* __restrict__ out)
{
  int r = blockIdx.x;
  const TI* p = in + (size_t)r * DD;
  float v[4], s = 0.f, sq = 0.f;
#pragma unroll
  for (int j = 0; j < 4; j++) {
    float x;
    if constexpr (std::is_same<TI, bf16>::value) x = b2f(p[threadIdx.x + j*256]);
    else x = p[threadIdx.x + j*256];
    v[j] = x; s += x; sq += x * x;
  }
  for (int o = 32; o > 0; o >>= 1) { s += __shfl_down(s, o, 64); sq += __shfl_down(sq, o, 64); }
  __shared__ float ls[4], lq[4];
  int w = threadIdx.x >> 6;
  if ((threadIdx.x & 63) == 0) { ls[w] = s; lq[w] = sq; }
  __syncthreads();
  s  = ls[0] + ls[1] + ls[2] + ls[3];
  sq = lq[0] + lq[1] + lq[2] + lq[3];
  float mu = s * (1.f / DD);
  float var = sq * (1.f / DD) - mu * mu;
  float rstd = rsqrtf(var + 1e-5f);
#pragma unroll
  for (int j = 0; j < 4; j++) {
    float o = (v[j] - mu) * rstd;
    if constexpr (std::is_same<TO, bf16>::value) out[(size_t)r*DD + threadIdx.x + j*256] = f2b(o);
    else out[(size_t)r*DD + threadIdx.x + j*256] = o;
  }
}

// ---------------- dots^T[n,s] = k[n]·q[s] * scale, softmax over s, col-sums ----------------
__global__ __launch_bounds__(256) void dots_softmax(const bf16* __restrict__ k,
    const float* __restrict__ q, float* __restrict__ attnT, float* __restrict__ colsum)
{
  __shared__ float qs[64][65];
  __shared__ float ks[64][65];
  __shared__ float cs[64];
  int t = threadIdx.x;
  int n0 = blockIdx.x * 64;
  int r = t >> 2, g = t & 3;
  float acc[16];
#pragma unroll
  for (int i = 0; i < 16; i++) acc[i] = 0.f;

  for (int d0 = 0; d0 < DD; d0 += 64) {
    for (int l = t; l < 4096; l += 256) {
      int a = l >> 6, b = l & 63;
      qs[a][b] = q[(size_t)a * DD + d0 + b];
      ks[a][b] = b2f(k[(size_t)(n0 + a) * DD + d0 + b]);
    }
    __syncthreads();
    for (int dd = 0; dd < 64; dd++) {
      float kv = ks[r][dd];
#pragma unroll
      for (int i = 0; i < 16; i++) acc[i] += kv * qs[g*16 + i][dd];
    }
    __syncthreads();
  }
  float m = -1e30f;
#pragma unroll
  for (int i = 0; i < 16; i++) { acc[i] *= 0.03125f; m = fmaxf(m, acc[i]); }
  m = fmaxf(m, __shfl_xor(m, 1, 64));
  m = fmaxf(m, __shfl_xor(m, 2, 64));
  float ssum = 0.f;
#pragma unroll
  for (int i = 0; i < 16; i++) { acc[i] = expf(acc[i] - m); ssum += acc[i]; }
  ssum += __shfl_xor(ssum, 1, 64);
  ssum += __shfl_xor(ssum, 2, 64);
  float inv = 1.f / ssum;
  if (t < 64) cs[t] = 0.f;
  __syncthreads();
#pragma unroll
  for (int i = 0; i < 16; i++) {
    float a = acc[i] * inv;
    attnT[(size_t)(n0 + r) * 64 + g*16 + i] = a;
    atomicAdd(&cs[g*16 + i], a);
  }
  __syncthreads();
  if (t < 64) atomicAdd(&colsum[t], cs[t]);
}

// ---------------- updates split-K partial: pbuf[kc][s][d] over 1024 rows ----------------
__global__ __launch_bounds__(256) void updates_partial(const float* __restrict__ attnT,
    const bf16* __restrict__ v, float* __restrict__ pbuf)
{
  __shared__ float at[64][65];
  __shared__ float vt[64][65];
  int t = threadIdx.x;
  int dt = blockIdx.x * 64;
  int kc = blockIdx.y;
  int s = t >> 2, g = t & 3;
  float acc[16];
#pragma unroll
  for (int i = 0; i < 16; i++) acc[i] = 0.f;

  for (int n0 = kc * 1024; n0 < kc * 1024 + 1024; n0 += 64) {
    for (int l = t; l < 4096; l += 256) {
      int a = l >> 6, b = l & 63;
      at[a][b] = attnT[(size_t)(n0 + a) * 64 + b];
      vt[a][b] = b2f(v[(size_t)(n0 + a) * DD + dt + b]);
    }
    __syncthreads();
    for (int nr = 0; nr < 64; nr++) {
      float a = at[nr][s];
#pragma unroll
      for (int i = 0; i < 16; i++) acc[i] += a * vt[nr][g*16 + i];
    }
    __syncthreads();
  }
#pragma unroll
  for (int i = 0; i < 16; i++)
    pbuf[((size_t)(kc * 64) + s) * DD + dt + g*16 + i] = acc[i];
}

__global__ __launch_bounds__(256) void updates_reduce(const float* __restrict__ pbuf,
    const float* __restrict__ colsum, float* __restrict__ upd)
{
  int gid = blockIdx.x * 256 + threadIdx.x;   // 65536
  int s = gid >> 10, d = gid & 1023;
  float sum = 0.f;
#pragma unroll
  for (int c = 0; c < 16; c++) sum += pbuf[((size_t)(c * 64) + s) * DD + d];
  upd[(size_t)s * DD + d] = sum / (colsum[s] + 1e-8f);
}

// ---------------- small-M GEMM: C[64,Ncol] = A[64,Kd] @ B (+bias, epilogue) ----------------
template<bool BT, int EPI>
__global__ __launch_bounds__(256) void gemm_smallM(const float* __restrict__ A, int Kd,
    const float* __restrict__ B, const float* __restrict__ bias,
    float* __restrict__ C, const float* __restrict__ resid, int Ncol)
{
  __shared__ float As[64][65];
  __shared__ float Bs[64][65];
  int t = threadIdx.x;
  int j0 = blockIdx.x * 64;
  int s = t >> 2, g = t & 3;
  float acc[16];
#pragma unroll
  for (int i = 0; i < 16; i++) acc[i] = 0.f;

  for (int d0 = 0; d0 < Kd; d0 += 64) {
    for (int l = t; l < 4096; l += 256) {
      int a = l >> 6, b = l & 63;
      As[a][b] = A[(size_t)a * Kd + d0 + b];
      if (BT) Bs[b][a] = B[(size_t)(j0 + a) * Kd + d0 + b];
      else    Bs[a][b] = B[(size_t)(d0 + a) * Ncol + j0 + b];
    }
    __syncthreads();
    for (int dd = 0; dd < 64; dd++) {
      float a = As[s][dd];
#pragma unroll
      for (int i = 0; i < 16; i++) acc[i] += a * Bs[dd][g*16 + i];
    }
    __syncthreads();
  }
#pragma unroll
  for (int i = 0; i < 16; i++) {
    int j = j0 + g*16 + i;
    float v = acc[i] + bias[j];
    if (EPI == 1) v = fmaxf(v, 0.f);
    if (EPI == 2) v += resid[(size_t)s * Ncol + j];
    C[(size_t)s * Ncol + j] = v;
  }
}

// ---------------- misc elementwise ----------------
__global__ void slots_init_k(const float* __restrict__ mu, const float* __restrict__ noise,
                             float* __restrict__ slots)
{
  int gid = blockIdx.x * 256 + threadIdx.x;  // 65536
  int d = gid & 1023;
  slots[gid] = mu[d] + noise[gid];
}

__global__ void gru_gate(const float* __restrict__ gi, const float* __restrict__ gh,
                         const float* __restrict__ hprev, float* __restrict__ out)
{
  int gid = blockIdx.x * 256 + threadIdx.x;  // 65536
  int s = gid >> 10, d = gid & 1023;
  float ir = gi[(size_t)s*TD + d],        hr = gh[(size_t)s*TD + d];
  float iz = gi[(size_t)s*TD + 1024 + d], hz = gh[(size_t)s*TD + 1024 + d];
  float in_ = gi[(size_t)s*TD + 2048 + d], hn = gh[(size_t)s*TD + 2048 + d];
  float r = 1.f / (1.f + expf(-(ir + hr)));
  float z = 1.f / (1.f + expf(-(iz + hz)));
  float n = tanhf(in_ + r * hn);
  float h = hprev[gid];
  out[gid] = (1.f - z) * n + z * h;
}

__global__ __launch_bounds__(256) void rownorm(const float* __restrict__ in, float* __restrict__ out)
{
  int r = blockIdx.x;
  const float* p = in + (size_t)r * DD;
  float v[4], sq = 0.f;
#pragma unroll
  for (int j = 0; j < 4; j++) { v[j] = p[threadIdx.x + j*256]; sq += v[j]*v[j]; }
  for (int o = 32; o > 0; o >>= 1) sq += __shfl_down(sq, o, 64);
  __shared__ float lq[4];
  int w = threadIdx.x >> 6;
  if ((threadIdx.x & 63) == 0) lq[w] = sq;
  __syncthreads();
  sq = lq[0] + lq[1] + lq[2] + lq[3];
  float sc = 1.f / (sqrtf(sq) + 1e-8f);
#pragma unroll
  for (int j = 0; j < 4; j++) out[(size_t)r*DD + threadIdx.x + j*256] = v[j] * sc;
}

__global__ __launch_bounds__(256) void sim_kernel(const float* __restrict__ an,
    const float* __restrict__ bn, float* __restrict__ simout)
{
  __shared__ float ar[1024];
  int i = blockIdx.x;
  for (int l = threadIdx.x; l < 1024; l += 256) ar[l] = an[(size_t)i * DD + l];
  __syncthreads();
  int j = threadIdx.x >> 2, g = threadIdx.x & 3;
  float sum = 0.f;
  for (int d = g; d < 1024; d += 4) sum += ar[d] * bn[(size_t)j * DD + d];
  sum += __shfl_xor(sum, 1, 64);
  sum += __shfl_xor(sum, 2, 64);
  if (g == 0) simout[i * 64 + j] = sum;
}

__global__ void match_kernel(const float* __restrict__ sim, float* __restrict__ outm)
{
  __shared__ float m[64];
  __shared__ int idx[64];
  __shared__ int order[64];
  __shared__ int used[64];
  int i = threadIdx.x;   // 64 threads
  float best = -1e30f; int bj = 0;
  for (int j = 0; j < 64; j++) {
    float v = sim[i * 64 + j];
    if (v > best) { best = v; bj = j; }
  }
  m[i] = best; idx[i] = bj; used[i] = 0;
  __syncthreads();
  int cnt = 0;
  for (int j = 0; j < 64; j++) {
    float mj = m[j];
    if (mj > best || (mj == best && j < i)) cnt++;
  }
  order[cnt] = i;
  __syncthreads();
  if (i == 0) {
    for (int r = 0; r < 64; r++) {
      int ii = order[r];
      int j = idx[ii];
      bool ok = (!used[j]) && (m[ii] > 0.3f);
      outm[ii] = ok ? (float)j : -1.0f;
      if (ok) used[j] = 1;
    }
  }
}

// ---------------- workspace layout (bytes) ----------------
// 0..64MB region: x_pre bf16 [0,32MB); attnT 4MB @0 and pbuf 4MB @8MB alias it during iters;
// persistent-in-launch: Wenc_t @32MB, Wk_t, Wv_t, dets_bf (all < 64MB)
static constexpr size_t OFF_SH  = 0;
static constexpr size_t OFF_PB  = (size_t)8 << 20;
static constexpr size_t OFF_WET = 33554432;                // 512KB
static constexpr size_t OFF_WKT = OFF_WET + 524288;        // 2MB
static constexpr size_t OFF_WVT = OFF_WKT + 2097152;       // 2MB
static constexpr size_t OFF_DBF = OFF_WVT + 2097152;       // 8MB  (ends ~46.7MB < 64MB)
static constexpr size_t OFF_X   = 67108864;                // x bf16 32MB
static constexpr size_t OFF_K   = OFF_X   + 33554432;      // k bf16 32MB
static constexpr size_t OFF_V   = OFF_K   + 33554432;      // v bf16 32MB
static constexpr size_t OFF_SL  = OFF_V   + 33554432;
static constexpr size_t OFF_SLP = OFF_SL  + 262144;
static constexpr size_t OFF_PRV = OFF_SLP + 262144;
static constexpr size_t OFF_LN  = OFF_PRV + 262144;
static constexpr size_t OFF_Q   = OFF_LN  + 262144;
static constexpr size_t OFF_UPD = OFF_Q   + 262144;
static constexpr size_t OFF_GI  = OFF_UPD + 262144;
static constexpr size_t OFF_GH  = OFF_GI  + 786432;
static constexpr size_t OFF_HID = OFF_GH  + 786432;
static constexpr size_t OFF_AN  = OFF_HID + 524288;
static constexpr size_t OFF_BN  = OFF_AN  + 262144;
static constexpr size_t OFF_CS  = OFF_BN  + 262144;

extern "C" void kernel_launch(void* const* d_in, const int* in_sizes, int n_in,
                              void* d_out, int out_size, void* d_ws, size_t ws_size,
                              hipStream_t stream)
{
  (void)in_sizes; (void)n_in; (void)out_size; (void)ws_size;
  const float* dets_t   = (const float*)d_in[0];
  const float* dets_t1  = (const float*)d_in[1];
  const float* W_enc    = (const float*)d_in[2];
  const float* b_enc    = (const float*)d_in[3];
  const float* Wq       = (const float*)d_in[4];
  const float* bq       = (const float*)d_in[5];
  const float* Wk       = (const float*)d_in[6];
  const float* bk       = (const float*)d_in[7];
  const float* Wv       = (const float*)d_in[8];
  const float* bv       = (const float*)d_in[9];
  const float* Wi       = (const float*)d_in[10];
  const float* Wh       = (const float*)d_in[11];
  const float* bi       = (const float*)d_in[12];
  const float* bh       = (const float*)d_in[13];
  const float* W1       = (const float*)d_in[14];
  const float* b1       = (const float*)d_in[15];
  const float* W2       = (const float*)d_in[16];
  const float* b2       = (const float*)d_in[17];
  const float* slots_mu = (const float*)d_in[18];
  const float* init_noise = (const float*)d_in[19];

  char* ws = (char*)d_ws;
  bf16*  x_pre  = (bf16*)(ws + OFF_SH);
  float* attnT  = (float*)(ws + OFF_SH);
  float* pbuf   = (float*)(ws + OFF_PB);
  bf16*  Wenc_t = (bf16*)(ws + OFF_WET);
  bf16*  Wk_t   = (bf16*)(ws + OFF_WKT);
  bf16*  Wv_t   = (bf16*)(ws + OFF_WVT);
  bf16*  dets_bf= (bf16*)(ws + OFF_DBF);
  bf16*  x      = (bf16*)(ws + OFF_X);
  bf16*  kbuf   = (bf16*)(ws + OFF_K);
  bf16*  vbuf   = (bf16*)(ws + OFF_V);
  float* slots  = (float*)(ws + OFF_SL);
  float* slotsp = (float*)(ws + OFF_SLP);
  float* prevs  = (float*)(ws + OFF_PRV);
  float* lnbuf  = (float*)(ws + OFF_LN);
  float* qbuf   = (float*)(ws + OFF_Q);
  float* upd    = (float*)(ws + OFF_UPD);
  float* gi     = (float*)(ws + OFF_GI);
  float* gh     = (float*)(ws + OFF_GH);
  float* hid    = (float*)(ws + OFF_HID);
  float* an     = (float*)(ws + OFF_AN);
  float* bn     = (float*)(ws + OFF_BN);
  float* colsum = (float*)(ws + OFF_CS);

  // one-time per launch: weights -> bf16 transposed [N][K]
  transpose_w<<<dim3(32,  8), 256, 0, stream>>>(W_enc, Wenc_t, DIN, DD);
  transpose_w<<<dim3(32, 32), 256, 0, stream>>>(Wk,    Wk_t,   DD,  DD);
  transpose_w<<<dim3(32, 32), 256, 0, stream>>>(Wv,    Wv_t,   DD,  DD);

  auto frame = [&](const float* dets, bool first) {
    f32_to_bf16_v<<<(N_DET*DIN)/1024, 256, 0, stream>>>(dets, dets_bf, N_DET*DIN);
    gemm_mfma_bt<bf16><<<dim3(8, 128), 256, 0, stream>>>(dets_bf, Wenc_t, b_enc, x_pre, N_DET, DD, DIN);
    ln_rows<bf16, bf16><<<N_DET, 256, 0, stream>>>(x_pre, x);
    gemm_mfma_bt<bf16><<<dim3(8, 128), 256, 0, stream>>>(x, Wk_t, bk, kbuf, N_DET, DD, DD);
    gemm_mfma_bt<bf16><<<dim3(8, 128), 256, 0, stream>>>(x, Wv_t, bv, vbuf, N_DET, DD, DD);
    if (first) slots_init_k<<<256, 256, 0, stream>>>(slots_mu, init_noise, slots);
    for (int it = 0; it < 3; ++it) {
      hipMemcpyAsync(slotsp, slots, 262144, hipMemcpyDeviceToDevice, stream);
      ln_rows<float, float><<<KSLOT, 256, 0, stream>>>(slots, lnbuf);
      gemm_smallM<false, 0><<<16, 256, 0, stream>>>(lnbuf, DD, Wq, bq, qbuf, nullptr, DD);
      hipMemsetAsync(colsum, 0, 256, stream);
      dots_softmax<<<256, 256, 0, stream>>>(kbuf, qbuf, attnT, colsum);
      updates_partial<<<dim3(16, 16), 256, 0, stream>>>(attnT, vbuf, pbuf);
      updates_reduce<<<256, 256, 0, stream>>>(pbuf, colsum, upd);
      gemm_smallM<true, 0><<<48, 256, 0, stream>>>(upd, DD, Wi, bi, gi, nullptr, TD);
      gemm_smallM<true, 0><<<48, 256, 0, stream>>>(slotsp, DD, Wh, bh, gh, nullptr, TD);
      gru_gate<<<256, 256, 0, stream>>>(gi, gh, slotsp, slots);
      ln_rows<float, float><<<KSLOT, 256, 0, stream>>>(slots, lnbuf);
      gemm_smallM<false, 1><<<32, 256, 0, stream>>>(lnbuf, DD, W1, b1, hid, nullptr, HH);
      gemm_smallM<false, 2><<<16, 256, 0, stream>>>(hid, HH, W2, b2, slots, slots, DD);
    }
  };

  frame(dets_t, true);
  hipMemcpyAsync(prevs, slots, 262144, hipMemcpyDeviceToDevice, stream);
  frame(dets_t1, false);

  rownorm<<<KSLOT, 256, 0, stream>>>(prevs, an);
  rownorm<<<KSLOT, 256, 0, stream>>>(slots, bn);
  float* outf = (float*)d_out;
  sim_kernel<<<KSLOT, 256, 0, stream>>>(an, bn, outf + 64);
  match_kernel<<<1, 64, 0, stream>>>(outf + 64, outf);
}

// Round 3
// 2435.774 us; speedup vs baseline: 4.3282x; 3.2173x over previous
//
#include <hip/hip_runtime.h>
#include <hip/hip_bf16.h>
#include <type_traits>

typedef __hip_bfloat16 bf16;
typedef __attribute__((ext_vector_type(8))) short s16x8;   // 8 bf16 (4 VGPRs)
typedef __attribute__((ext_vector_type(4))) float f32x4;

#define N_DET 16384
#define DIN   256
#define DD    1024
#define KSLOT 64
#define HH    2048
#define TD    3072

__device__ __forceinline__ float b2f(bf16 x){ return __bfloat162float(x); }
__device__ __forceinline__ bf16  f2b(float x){ return __float2bfloat16(x); }

__device__ __forceinline__ void gload_lds16(const void* g, void* l) {
  __builtin_amdgcn_global_load_lds(
      (const __attribute__((address_space(1))) unsigned int*)g,
      (__attribute__((address_space(3))) unsigned int*)l, 16, 0, 0);
}

// ---------------- MFMA GEMM: C[M,N] = A[M,K] @ Bt[N,K]^T + bias ----------------
// m97 structure: 128x128 tile, BK=32, 256 thr = 4 waves, each wave 64x64 (4x4 frags 16x16x32)
template<typename TO>
__global__ __launch_bounds__(256) void gemm_mfma_bt(
    const bf16* __restrict__ A, const bf16* __restrict__ Bt,
    const float* __restrict__ bias, TO* __restrict__ C, int M, int N, int K)
{
  __shared__ bf16 As[128*32];
  __shared__ bf16 Bs[128*32];
  const int bm = blockIdx.y * 128, bn = blockIdx.x * 128;
  const int lane = threadIdx.x & 63, wave = threadIdx.x >> 6;
  const int wr = wave >> 1, wc = wave & 1;   // wave's 64x64 sub-tile

  f32x4 acc[4][4];
  const f32x4 zero = {0.f, 0.f, 0.f, 0.f};
#pragma unroll
  for (int m = 0; m < 4; ++m)
#pragma unroll
    for (int n = 0; n < 4; ++n) acc[m][n] = zero;

  for (int k0 = 0; k0 < K; k0 += 32) {
    __syncthreads();
#pragma unroll
    for (int c = 0; c < 2; ++c) {
      int i = wave * 64 + c * 256 + lane;
      int r = i >> 2, q = i & 3;
      gload_lds16(A + (size_t)(bm + r) * K + k0 + q * 8,
                  As + (size_t)(wave * 64 + c * 256) * 8);
    }
#pragma unroll
    for (int c = 0; c < 2; ++c) {
      int i = wave * 64 + c * 256 + lane;
      int r = i >> 2, q = i & 3;
      gload_lds16(Bt + (size_t)(bn + r) * K + k0 + q * 8,
                  Bs + (size_t)(wave * 64 + c * 256) * 8);
    }
    __syncthreads();

    s16x8 af[4], bfr[4];
#pragma unroll
    for (int m = 0; m < 4; ++m)
      af[m] = *(const s16x8*)&As[(wr * 64 + m * 16 + (lane & 15)) * 32 + (lane >> 4) * 8];
#pragma unroll
    for (int n = 0; n < 4; ++n)
      bfr[n] = *(const s16x8*)&Bs[(wc * 64 + n * 16 + (lane & 15)) * 32 + (lane >> 4) * 8];
#pragma unroll
    for (int m = 0; m < 4; ++m)
#pragma unroll
      for (int n = 0; n < 4; ++n)
        acc[m][n] = __builtin_amdgcn_mfma_f32_16x16x32_bf16(af[m], bfr[n], acc[m][n], 0, 0, 0);
  }

#pragma unroll
  for (int m = 0; m < 4; ++m)
#pragma unroll
    for (int n = 0; n < 4; ++n) {
      int col = bn + wc * 64 + n * 16 + (lane & 15);
      float bv = bias[col];
#pragma unroll
      for (int j = 0; j < 4; ++j) {
        int row = bm + wr * 64 + m * 16 + (lane >> 4) * 4 + j;
        float v = acc[m][n][j] + bv;
        if constexpr (std::is_same<TO, bf16>::value)
          C[(size_t)row * N + col] = f2b(v);
        else
          C[(size_t)row * N + col] = v;
      }
    }
}

// ---------------- skinny split-K MFMA GEMM: partial[sk][64][N] = A[64,Kc]@Bt[N,Kc]^T ----------------
// grid (N/64, SK), Kc = 128. 4 waves; wave w computes 64(M) x 16(N) cols [w*16, w*16+16).
template<int SK>
__global__ __launch_bounds__(256) void gemm_skinny(
    const bf16* __restrict__ A, const bf16* __restrict__ Bt,
    float* __restrict__ pbuf, int N, int K)
{
  __shared__ bf16 As[4*64*32];   // [ks][row][32]
  __shared__ bf16 Bs[4*64*32];   // [ks][col][32]
  const int lane = threadIdx.x & 63, wave = threadIdx.x >> 6;
  const int n0 = blockIdx.x * 64;
  const int kb = blockIdx.y * 128;

  // stage A: 1024 chunks of 16B (4 per thread); chunk c -> ks=c>>8, r=(c&255)>>2, q=c&3
#pragma unroll
  for (int g = 0; g < 4; ++g) {
    int rem = wave * 64 + lane;          // ks = g (wave-uniform)
    int r = rem >> 2, q = rem & 3;
    gload_lds16(A + (size_t)r * K + kb + g * 32 + q * 8,
                As + ((size_t)g * 256 + wave * 64) * 8);
  }
#pragma unroll
  for (int g = 0; g < 4; ++g) {
    int rem = wave * 64 + lane;
    int r = rem >> 2, q = rem & 3;
    gload_lds16(Bt + (size_t)(n0 + r) * K + kb + g * 32 + q * 8,
                Bs + ((size_t)g * 256 + wave * 64) * 8);
  }
  __syncthreads();

  f32x4 acc[4];
  const f32x4 zero = {0.f, 0.f, 0.f, 0.f};
#pragma unroll
  for (int m = 0; m < 4; ++m) acc[m] = zero;

  const int l15 = lane & 15, h = lane >> 4;
#pragma unroll
  for (int ks = 0; ks < 4; ++ks) {
    s16x8 bfr = *(const s16x8*)&Bs[(ks * 64 + wave * 16 + l15) * 32 + h * 8];
#pragma unroll
    for (int m = 0; m < 4; ++m) {
      s16x8 af = *(const s16x8*)&As[(ks * 64 + m * 16 + l15) * 32 + h * 8];
      acc[m] = __builtin_amdgcn_mfma_f32_16x16x32_bf16(af, bfr, acc[m], 0, 0, 0);
    }
  }

  float* pout = pbuf + (size_t)(blockIdx.y * 64) * N;
#pragma unroll
  for (int m = 0; m < 4; ++m)
#pragma unroll
    for (int j = 0; j < 4; ++j) {
      int row = m * 16 + h * 4 + j;
      int col = n0 + wave * 16 + l15;
      pout[(size_t)row * N + col] = acc[m][j];
    }
}

// ---------------- skinny reduce: out[64][N] = sum_sk partial + bias (+epilogue) ----------------
// EPI: 0 = store fp32; 1 = relu -> bf16; 2 = +resid -> fp32
template<int SK, int EPI>
__global__ __launch_bounds__(256) void skinny_reduce(const float* __restrict__ pbuf,
    const float* __restrict__ bias, const float* __restrict__ resid,
    float* __restrict__ outf, bf16* __restrict__ outb, int N)
{
  int s = blockIdx.y, n = blockIdx.x * 256 + threadIdx.x;
  float v = bias[n];
#pragma unroll
  for (int sk = 0; sk < SK; ++sk) v += pbuf[(size_t)(sk * 64 + s) * N + n];
  if (EPI == 1) v = fmaxf(v, 0.f);
  if (EPI == 2) v += resid[(size_t)s * N + n];
  if (outf) outf[(size_t)s * N + n] = v;
  if (outb) outb[(size_t)s * N + n] = f2b(v);
}

// ---------------- fused GRU reduce: reduces gi/gh partials + gates + blend ----------------
template<int SK>
__global__ __launch_bounds__(256) void gru_reduce(const float* __restrict__ pA,
    const float* __restrict__ pB, const float* __restrict__ bi,
    const float* __restrict__ bh, const float* __restrict__ hprev,
    float* __restrict__ slots)
{
  int s = blockIdx.y, d = blockIdx.x * 256 + threadIdx.x;   // grid (4, 64)
  float ir = bi[d], iz = bi[1024 + d], in_ = bi[2048 + d];
  float hr = bh[d], hz = bh[1024 + d], hn = bh[2048 + d];
#pragma unroll
  for (int sk = 0; sk < SK; ++sk) {
    const float* a = pA + (size_t)(sk * 64 + s) * TD;
    const float* b = pB + (size_t)(sk * 64 + s) * TD;
    ir += a[d]; iz += a[1024 + d]; in_ += a[2048 + d];
    hr += b[d]; hz += b[1024 + d]; hn += b[2048 + d];
  }
  float r = 1.f / (1.f + expf(-(ir + hr)));
  float z = 1.f / (1.f + expf(-(iz + hz)));
  float nn = tanhf(in_ + r * hn);
  float h = hprev[(size_t)s * DD + d];
  slots[(size_t)s * DD + d] = (1.f - z) * nn + z * h;
}

// ---------------- weight transpose+convert: W[K][N] f32 -> Wt[N][K] bf16 ----------------
__global__ __launch_bounds__(256) void transpose_w(const float* __restrict__ W,
                                                   bf16* __restrict__ Wt, int K, int N)
{
  __shared__ float t[32][33];
  int n0 = blockIdx.x * 32, k0 = blockIdx.y * 32;
  int tx = threadIdx.x & 31, ty = threadIdx.x >> 5;
  for (int r = ty; r < 32; r += 8)
    t[r][tx] = W[(size_t)(k0 + r) * N + n0 + tx];
  __syncthreads();
  for (int r = ty; r < 32; r += 8)
    Wt[(size_t)(n0 + r) * K + k0 + tx] = f2b(t[tx][r]);
}

__global__ void f32_to_bf16_v(const float* __restrict__ in, bf16* __restrict__ out, int n)
{
  int i = (blockIdx.x * 256 + threadIdx.x) * 4;
  if (i < n) {
    float4 v = *(const float4*)(in + i);
    bf16 o[4] = {f2b(v.x), f2b(v.y), f2b(v.z), f2b(v.w)};
    *(ushort4*)(out + i) = *(const ushort4*)o;
  }
}

// ---------------- layernorm over rows of [R, 1024] -> bf16 ----------------
template<typename TI>
__global__ __launch_bounds__(256) void ln_rows(const TI* __restrict__ in, bf16* __restrict__ out)
{
  int r = blockIdx.x;
  const TI* p = in + (size_t)r * DD;
  float v[4], s = 0.f, sq = 0.f;
#pragma unroll
  for (int j = 0; j < 4; j++) {
    float x;
    if constexpr (std::is_same<TI, bf16>::value) x = b2f(p[threadIdx.x + j*256]);
    else x = p[threadIdx.x + j*256];
    v[j] = x; s += x; sq += x * x;
  }
  for (int o = 32; o > 0; o >>= 1) { s += __shfl_down(s, o, 64); sq += __shfl_down(sq, o, 64); }
  __shared__ float ls[4], lq[4];
  int w = threadIdx.x >> 6;
  if ((threadIdx.x & 63) == 0) { ls[w] = s; lq[w] = sq; }
  __syncthreads();
  s  = ls[0] + ls[1] + ls[2] + ls[3];
  sq = lq[0] + lq[1] + lq[2] + lq[3];
  float mu = s * (1.f / DD);
  float var = sq * (1.f / DD) - mu * mu;
  float rstd = rsqrtf(var + 1e-5f);
#pragma unroll
  for (int j = 0; j < 4; j++)
    out[(size_t)r*DD + threadIdx.x + j*256] = f2b((v[j] - mu) * rstd);
}

// ---------------- dots^T[n,s] = k[n]·q[s] * scale, softmax over s, col-sums ----------------
__global__ __launch_bounds__(256) void dots_softmax(const bf16* __restrict__ k,
    const float* __restrict__ q, float* __restrict__ attnT, float* __restrict__ colsum)
{
  __shared__ float qs[64][65];
  __shared__ float ks[64][65];
  __shared__ float cs[64];
  int t = threadIdx.x;
  int n0 = blockIdx.x * 64;
  int r = t >> 2, g = t & 3;
  float acc[16];
#pragma unroll
  for (int i = 0; i < 16; i++) acc[i] = 0.f;

  for (int d0 = 0; d0 < DD; d0 += 64) {
    for (int l = t; l < 4096; l += 256) {
      int a = l >> 6, b = l & 63;
      qs[a][b] = q[(size_t)a * DD + d0 + b];
      ks[a][b] = b2f(k[(size_t)(n0 + a) * DD + d0 + b]);
    }
    __syncthreads();
    for (int dd = 0; dd < 64; dd++) {
      float kv = ks[r][dd];
#pragma unroll
      for (int i = 0; i < 16; i++) acc[i] += kv * qs[g*16 + i][dd];
    }
    __syncthreads();
  }
  float m = -1e30f;
#pragma unroll
  for (int i = 0; i < 16; i++) { acc[i] *= 0.03125f; m = fmaxf(m, acc[i]); }
  m = fmaxf(m, __shfl_xor(m, 1, 64));
  m = fmaxf(m, __shfl_xor(m, 2, 64));
  float ssum = 0.f;
#pragma unroll
  for (int i = 0; i < 16; i++) { acc[i] = expf(acc[i] - m); ssum += acc[i]; }
  ssum += __shfl_xor(ssum, 1, 64);
  ssum += __shfl_xor(ssum, 2, 64);
  float inv = 1.f / ssum;
  if (t < 64) cs[t] = 0.f;
  __syncthreads();
#pragma unroll
  for (int i = 0; i < 16; i++) {
    float a = acc[i] * inv;
    attnT[(size_t)(n0 + r) * 64 + g*16 + i] = a;
    atomicAdd(&cs[g*16 + i], a);
  }
  __syncthreads();
  if (t < 64) atomicAdd(&colsum[t], cs[t]);
}

// ---------------- updates split-K partial: pbuf[kc][s][d] over 1024 rows ----------------
__global__ __launch_bounds__(256) void updates_partial(const float* __restrict__ attnT,
    const bf16* __restrict__ v, float* __restrict__ pbuf)
{
  __shared__ float at[64][65];
  __shared__ float vt[64][65];
  int t = threadIdx.x;
  int dt = blockIdx.x * 64;
  int kc = blockIdx.y;
  int s = t >> 2, g = t & 3;
  float acc[16];
#pragma unroll
  for (int i = 0; i < 16; i++) acc[i] = 0.f;

  for (int n0 = kc * 1024; n0 < kc * 1024 + 1024; n0 += 64) {
    for (int l = t; l < 4096; l += 256) {
      int a = l >> 6, b = l & 63;
      at[a][b] = attnT[(size_t)(n0 + a) * 64 + b];
      vt[a][b] = b2f(v[(size_t)(n0 + a) * DD + dt + b]);
    }
    __syncthreads();
    for (int nr = 0; nr < 64; nr++) {
      float a = at[nr][s];
#pragma unroll
      for (int i = 0; i < 16; i++) acc[i] += a * vt[nr][g*16 + i];
    }
    __syncthreads();
  }
#pragma unroll
  for (int i = 0; i < 16; i++)
    pbuf[((size_t)(kc * 64) + s) * DD + dt + g*16 + i] = acc[i];
}

__global__ __launch_bounds__(256) void updates_reduce(const float* __restrict__ pbuf,
    const float* __restrict__ colsum, bf16* __restrict__ updb)
{
  int gid = blockIdx.x * 256 + threadIdx.x;   // 65536
  int s = gid >> 10, d = gid & 1023;
  float sum = 0.f;
#pragma unroll
  for (int c = 0; c < 16; c++) sum += pbuf[((size_t)(c * 64) + s) * DD + d];
  updb[(size_t)s * DD + d] = f2b(sum / (colsum[s] + 1e-8f));
}

// ---------------- misc ----------------
__global__ void slots_init_k(const float* __restrict__ mu, const float* __restrict__ noise,
                             float* __restrict__ slots)
{
  int gid = blockIdx.x * 256 + threadIdx.x;  // 65536
  int d = gid & 1023;
  slots[gid] = mu[d] + noise[gid];
}

__global__ void copy_slots_k(const float* __restrict__ in, float* __restrict__ outf,
                             bf16* __restrict__ outb)
{
  int gid = blockIdx.x * 256 + threadIdx.x;  // 65536
  float v = in[gid];
  outf[gid] = v;
  outb[gid] = f2b(v);
}

__global__ __launch_bounds__(256) void rownorm(const float* __restrict__ in, float* __restrict__ out)
{
  int r = blockIdx.x;
  const float* p = in + (size_t)r * DD;
  float v[4], sq = 0.f;
#pragma unroll
  for (int j = 0; j < 4; j++) { v[j] = p[threadIdx.x + j*256]; sq += v[j]*v[j]; }
  for (int o = 32; o > 0; o >>= 1) sq += __shfl_down(sq, o, 64);
  __shared__ float lq[4];
  int w = threadIdx.x >> 6;
  if ((threadIdx.x & 63) == 0) lq[w] = sq;
  __syncthreads();
  sq = lq[0] + lq[1] + lq[2] + lq[3];
  float sc = 1.f / (sqrtf(sq) + 1e-8f);
#pragma unroll
  for (int j = 0; j < 4; j++) out[(size_t)r*DD + threadIdx.x + j*256] = v[j] * sc;
}

__global__ __launch_bounds__(256) void sim_kernel(const float* __restrict__ an,
    const float* __restrict__ bn, float* __restrict__ simout)
{
  __shared__ float ar[1024];
  int i = blockIdx.x;
  for (int l = threadIdx.x; l < 1024; l += 256) ar[l] = an[(size_t)i * DD + l];
  __syncthreads();
  int j = threadIdx.x >> 2, g = threadIdx.x & 3;
  float sum = 0.f;
  for (int d = g; d < 1024; d += 4) sum += ar[d] * bn[(size_t)j * DD + d];
  sum += __shfl_xor(sum, 1, 64);
  sum += __shfl_xor(sum, 2, 64);
  if (g == 0) simout[i * 64 + j] = sum;
}

__global__ void match_kernel(const float* __restrict__ sim, float* __restrict__ outm)
{
  __shared__ float m[64];
  __shared__ int idx[64];
  __shared__ int order[64];
  __shared__ int used[64];
  int i = threadIdx.x;   // 64 threads
  float best = -1e30f; int bj = 0;
  for (int j = 0; j < 64; j++) {
    float v = sim[i * 64 + j];
    if (v > best) { best = v; bj = j; }
  }
  m[i] = best; idx[i] = bj; used[i] = 0;
  __syncthreads();
  int cnt = 0;
  for (int j = 0; j < 64; j++) {
    float mj = m[j];
    if (mj > best || (mj == best && j < i)) cnt++;
  }
  order[cnt] = i;
  __syncthreads();
  if (i == 0) {
    for (int r = 0; r < 64; r++) {
      int ii = order[r];
      int j = idx[ii];
      bool ok = (!used[j]) && (m[ii] > 0.3f);
      outm[ii] = ok ? (float)j : -1.0f;
      if (ok) used[j] = 1;
    }
  }
}

// ---------------- workspace layout (bytes) ----------------
// phase aliasing: [0,32MB) = x_pre (frame stage) OR {attnT 4MB, upb 4MB, pA 6MB, pB 6MB} (iters)
//                 [60MB, 68MB) = dets_bf (pre-enc) then x bf16 [60MB,92MB) overwrites it
static constexpr size_t OFF_ATT  = 0;
static constexpr size_t OFF_UPB  = (size_t)4  << 20;
static constexpr size_t OFF_PA   = (size_t)8  << 20;
static constexpr size_t OFF_PB2  = (size_t)14 << 20;
static constexpr size_t OFF_XPRE = 0;
static constexpr size_t OFF_WET  = (size_t)32 << 20;
static constexpr size_t OFF_WKT  = OFF_WET + ((size_t)512 << 10);
static constexpr size_t OFF_WVT  = OFF_WKT + ((size_t)2 << 20);
static constexpr size_t OFF_WQT  = OFF_WVT + ((size_t)2 << 20);
static constexpr size_t OFF_W1T  = OFF_WQT + ((size_t)2 << 20);
static constexpr size_t OFF_W2T  = OFF_W1T + ((size_t)4 << 20);
static constexpr size_t OFF_WIB  = OFF_W2T + ((size_t)4 << 20);
static constexpr size_t OFF_WHB  = OFF_WIB + ((size_t)6 << 20);   // ends 58.5MB
static constexpr size_t OFF_X    = (size_t)60 << 20;
static constexpr size_t OFF_DBF  = OFF_X;                          // alias (dead before x write)
static constexpr size_t OFF_K    = OFF_X + ((size_t)32 << 20);
static constexpr size_t OFF_V    = OFF_K + ((size_t)32 << 20);
static constexpr size_t OFF_SM   = OFF_V + ((size_t)32 << 20);     // 156MB small region
static constexpr size_t OFF_SL   = OFF_SM;
static constexpr size_t OFF_SLP  = OFF_SL  + 262144;
static constexpr size_t OFF_SLPB = OFF_SLP + 262144;
static constexpr size_t OFF_PRV  = OFF_SLPB+ 262144;
static constexpr size_t OFF_LNB  = OFF_PRV + 262144;
static constexpr size_t OFF_Q    = OFF_LNB + 262144;
static constexpr size_t OFF_UPDB = OFF_Q   + 262144;
static constexpr size_t OFF_HIDB = OFF_UPDB+ 262144;
static constexpr size_t OFF_AN   = OFF_HIDB+ 262144;
static constexpr size_t OFF_BN   = OFF_AN  + 262144;
static constexpr size_t OFF_CS   = OFF_BN  + 262144;

extern "C" void kernel_launch(void* const* d_in, const int* in_sizes, int n_in,
                              void* d_out, int out_size, void* d_ws, size_t ws_size,
                              hipStream_t stream)
{
  (void)in_sizes; (void)n_in; (void)out_size; (void)ws_size;
  const float* dets_t   = (const float*)d_in[0];
  const float* dets_t1  = (const float*)d_in[1];
  const float* W_enc    = (const float*)d_in[2];
  const float* b_enc    = (const float*)d_in[3];
  const float* Wq       = (const float*)d_in[4];
  const float* bq       = (const float*)d_in[5];
  const float* Wk       = (const float*)d_in[6];
  const float* bk       = (const float*)d_in[7];
  const float* Wv       = (const float*)d_in[8];
  const float* bv       = (const float*)d_in[9];
  const float* Wi       = (const float*)d_in[10];
  const float* Wh       = (const float*)d_in[11];
  const float* bi       = (const float*)d_in[12];
  const float* bh       = (const float*)d_in[13];
  const float* W1       = (const float*)d_in[14];
  const float* b1       = (const float*)d_in[15];
  const float* W2       = (const float*)d_in[16];
  const float* b2       = (const float*)d_in[17];
  const float* slots_mu = (const float*)d_in[18];
  const float* init_noise = (const float*)d_in[19];

  char* ws = (char*)d_ws;
  bf16*  x_pre  = (bf16*)(ws + OFF_XPRE);
  float* attnT  = (float*)(ws + OFF_ATT);
  float* upb    = (float*)(ws + OFF_UPB);
  float* pA     = (float*)(ws + OFF_PA);
  float* pB     = (float*)(ws + OFF_PB2);
  bf16*  Wenc_t = (bf16*)(ws + OFF_WET);
  bf16*  Wk_t   = (bf16*)(ws + OFF_WKT);
  bf16*  Wv_t   = (bf16*)(ws + OFF_WVT);
  bf16*  Wq_t   = (bf16*)(ws + OFF_WQT);
  bf16*  W1_t   = (bf16*)(ws + OFF_W1T);
  bf16*  W2_t   = (bf16*)(ws + OFF_W2T);
  bf16*  Wi_b   = (bf16*)(ws + OFF_WIB);
  bf16*  Wh_b   = (bf16*)(ws + OFF_WHB);
  bf16*  dets_bf= (bf16*)(ws + OFF_DBF);
  bf16*  x      = (bf16*)(ws + OFF_X);
  bf16*  kbuf   = (bf16*)(ws + OFF_K);
  bf16*  vbuf   = (bf16*)(ws + OFF_V);
  float* slots  = (float*)(ws + OFF_SL);
  float* slotsp = (float*)(ws + OFF_SLP);
  bf16*  slotspb= (bf16*)(ws + OFF_SLPB);
  float* prevs  = (float*)(ws + OFF_PRV);
  bf16*  lnb    = (bf16*)(ws + OFF_LNB);
  float* qbuf   = (float*)(ws + OFF_Q);
  bf16*  updb   = (bf16*)(ws + OFF_UPDB);
  bf16*  hidb   = (bf16*)(ws + OFF_HIDB);
  float* an     = (float*)(ws + OFF_AN);
  float* bn     = (float*)(ws + OFF_BN);
  float* colsum = (float*)(ws + OFF_CS);

  // one-time per launch: weights -> bf16 (transposed to [N][K] where needed)
  transpose_w<<<dim3(32,  8), 256, 0, stream>>>(W_enc, Wenc_t, DIN, DD);
  transpose_w<<<dim3(32, 32), 256, 0, stream>>>(Wk,    Wk_t,   DD,  DD);
  transpose_w<<<dim3(32, 32), 256, 0, stream>>>(Wv,    Wv_t,   DD,  DD);
  transpose_w<<<dim3(32, 32), 256, 0, stream>>>(Wq,    Wq_t,   DD,  DD);
  transpose_w<<<dim3(64, 32), 256, 0, stream>>>(W1,    W1_t,   DD,  HH);
  transpose_w<<<dim3(32, 64), 256, 0, stream>>>(W2,    W2_t,   HH,  DD);
  f32_to_bf16_v<<<(TD*DD)/1024, 256, 0, stream>>>(Wi, Wi_b, TD*DD);   // Wi already [N,K]
  f32_to_bf16_v<<<(TD*DD)/1024, 256, 0, stream>>>(Wh, Wh_b, TD*DD);

  auto frame = [&](const float* dets, bool first) {
    f32_to_bf16_v<<<(N_DET*DIN)/1024, 256, 0, stream>>>(dets, dets_bf, N_DET*DIN);
    gemm_mfma_bt<bf16><<<dim3(8, 128), 256, 0, stream>>>(dets_bf, Wenc_t, b_enc, x_pre, N_DET, DD, DIN);
    ln_rows<bf16><<<N_DET, 256, 0, stream>>>(x_pre, x);
    gemm_mfma_bt<bf16><<<dim3(8, 128), 256, 0, stream>>>(x, Wk_t, bk, kbuf, N_DET, DD, DD);
    gemm_mfma_bt<bf16><<<dim3(8, 128), 256, 0, stream>>>(x, Wv_t, bv, vbuf, N_DET, DD, DD);
    if (first) slots_init_k<<<256, 256, 0, stream>>>(slots_mu, init_noise, slots);
    for (int it = 0; it < 3; ++it) {
      copy_slots_k<<<256, 256, 0, stream>>>(slots, slotsp, slotspb);
      ln_rows<float><<<KSLOT, 256, 0, stream>>>(slots, lnb);
      gemm_skinny<8><<<dim3(16, 8), 256, 0, stream>>>(lnb, Wq_t, pA, DD, DD);
      skinny_reduce<8, 0><<<dim3(4, 64), 256, 0, stream>>>(pA, bq, nullptr, qbuf, nullptr, DD);
      hipMemsetAsync(colsum, 0, 256, stream);
      dots_softmax<<<256, 256, 0, stream>>>(kbuf, qbuf, attnT, colsum);
      updates_partial<<<dim3(16, 16), 256, 0, stream>>>(attnT, vbuf, upb);
      updates_reduce<<<256, 256, 0, stream>>>(upb, colsum, updb);
      gemm_skinny<8><<<dim3(48, 8), 256, 0, stream>>>(updb,    Wi_b, pA, TD, DD);
      gemm_skinny<8><<<dim3(48, 8), 256, 0, stream>>>(slotspb, Wh_b, pB, TD, DD);
      gru_reduce<8><<<dim3(4, 64), 256, 0, stream>>>(pA, pB, bi, bh, slotsp, slots);
      ln_rows<float><<<KSLOT, 256, 0, stream>>>(slots, lnb);
      gemm_skinny<8><<<dim3(32, 8), 256, 0, stream>>>(lnb, W1_t, pA, HH, DD);
      skinny_reduce<8, 1><<<dim3(8, 64), 256, 0, stream>>>(pA, b1, nullptr, nullptr, hidb, HH);
      gemm_skinny<16><<<dim3(16, 16), 256, 0, stream>>>(hidb, W2_t, pA, DD, HH);
      skinny_reduce<16, 2><<<dim3(4, 64), 256, 0, stream>>>(pA, b2, slots, slots, nullptr, DD);
    }
  };

  frame(dets_t, true);
  hipMemcpyAsync(prevs, slots, 262144, hipMemcpyDeviceToDevice, stream);
  frame(dets_t1, false);

  rownorm<<<KSLOT, 256, 0, stream>>>(prevs, an);
  rownorm<<<KSLOT, 256, 0, stream>>>(slots, bn);
  float* outf = (float*)d_out;
  sim_kernel<<<KSLOT, 256, 0, stream>>>(an, bn, outf + 64);
  match_kernel<<<1, 64, 0, stream>>>(outf + 64, outf);
}

// Round 4
// 898.479 us; speedup vs baseline: 11.7337x; 2.7110x over previous
//
#include <hip/hip_runtime.h>
#include <hip/hip_bf16.h>
#include <type_traits>

typedef __hip_bfloat16 bf16;
typedef __attribute__((ext_vector_type(8))) short s16x8;   // 8 bf16 (4 VGPRs)
typedef __attribute__((ext_vector_type(4))) float f32x4;

#define N_DET 16384
#define DIN   256
#define DD    1024
#define KSLOT 64
#define HH    2048
#define TD    3072

__device__ __forceinline__ float b2f(bf16 x){ return __bfloat162float(x); }
__device__ __forceinline__ bf16  f2b(float x){ return __float2bfloat16(x); }

__device__ __forceinline__ void gload_lds16(const void* g, void* l) {
  __builtin_amdgcn_global_load_lds(
      (const __attribute__((address_space(1))) unsigned int*)g,
      (__attribute__((address_space(3))) unsigned int*)l, 16, 0, 0);
}

// ---------------- MFMA GEMM: C[M,N] = A[M,K] @ Bt[N,K]^T + bias ----------------
// TR=false: C[row*N+col]. TR=true: C^T stored as C[col*M+row] (bf16 only, packed 4-row stores)
template<typename TO, bool TR>
__global__ __launch_bounds__(256) void gemm_mfma_bt(
    const bf16* __restrict__ A, const bf16* __restrict__ Bt,
    const float* __restrict__ bias, TO* __restrict__ C, int M, int N, int K)
{
  __shared__ bf16 As[128*32];
  __shared__ bf16 Bs[128*32];
  const int bm = blockIdx.y * 128, bn = blockIdx.x * 128;
  const int lane = threadIdx.x & 63, wave = threadIdx.x >> 6;
  const int wr = wave >> 1, wc = wave & 1;

  f32x4 acc[4][4];
  const f32x4 zero = {0.f, 0.f, 0.f, 0.f};
#pragma unroll
  for (int m = 0; m < 4; ++m)
#pragma unroll
    for (int n = 0; n < 4; ++n) acc[m][n] = zero;

  for (int k0 = 0; k0 < K; k0 += 32) {
    __syncthreads();
#pragma unroll
    for (int c = 0; c < 2; ++c) {
      int i = wave * 64 + c * 256 + lane;
      int r = i >> 2, q = i & 3;
      gload_lds16(A + (size_t)(bm + r) * K + k0 + q * 8,
                  As + (size_t)(wave * 64 + c * 256) * 8);
    }
#pragma unroll
    for (int c = 0; c < 2; ++c) {
      int i = wave * 64 + c * 256 + lane;
      int r = i >> 2, q = i & 3;
      gload_lds16(Bt + (size_t)(bn + r) * K + k0 + q * 8,
                  Bs + (size_t)(wave * 64 + c * 256) * 8);
    }
    __syncthreads();

    s16x8 af[4], bfr[4];
#pragma unroll
    for (int m = 0; m < 4; ++m)
      af[m] = *(const s16x8*)&As[(wr * 64 + m * 16 + (lane & 15)) * 32 + (lane >> 4) * 8];
#pragma unroll
    for (int n = 0; n < 4; ++n)
      bfr[n] = *(const s16x8*)&Bs[(wc * 64 + n * 16 + (lane & 15)) * 32 + (lane >> 4) * 8];
#pragma unroll
    for (int m = 0; m < 4; ++m)
#pragma unroll
      for (int n = 0; n < 4; ++n)
        acc[m][n] = __builtin_amdgcn_mfma_f32_16x16x32_bf16(af[m], bfr[n], acc[m][n], 0, 0, 0);
  }

#pragma unroll
  for (int m = 0; m < 4; ++m)
#pragma unroll
    for (int n = 0; n < 4; ++n) {
      int col = bn + wc * 64 + n * 16 + (lane & 15);
      float bv = bias[col];
      if constexpr (TR) {
        int row0 = bm + wr * 64 + m * 16 + (lane >> 4) * 4;
        bf16 pk[4];
#pragma unroll
        for (int j = 0; j < 4; ++j) pk[j] = f2b(acc[m][n][j] + bv);
        *(ushort4*)((bf16*)C + (size_t)col * M + row0) = *(const ushort4*)pk;
      } else {
#pragma unroll
        for (int j = 0; j < 4; ++j) {
          int row = bm + wr * 64 + m * 16 + (lane >> 4) * 4 + j;
          float v = acc[m][n][j] + bv;
          if constexpr (std::is_same<TO, bf16>::value)
            C[(size_t)row * N + col] = f2b(v);
          else
            C[(size_t)row * N + col] = v;
        }
      }
    }
}

// ---------------- skinny split-K MFMA GEMM: partial[sk][64][N] = A[64,Kc]@Bt[N,Kc]^T ----------------
// grid (N/64, K/Kc). Per 128-K step: stage A[64][128]+B[64][128], 16 MFMA/wave.
__global__ __launch_bounds__(256) void gemm_skinny_loop(
    const bf16* __restrict__ A, const bf16* __restrict__ Bt,
    float* __restrict__ pbuf, int N, int K, int Kc)
{
  __shared__ bf16 As[4*64*32];   // [ks][row][32]
  __shared__ bf16 Bs[4*64*32];   // [ks][col][32]
  const int lane = threadIdx.x & 63, wave = threadIdx.x >> 6;
  const int n0 = blockIdx.x * 64;
  const int kb0 = blockIdx.y * Kc;
  const int rem = wave * 64 + lane;
  const int r = rem >> 2, q = rem & 3;
  const int l15 = lane & 15, h = lane >> 4;

  f32x4 acc[4];
  const f32x4 zero = {0.f, 0.f, 0.f, 0.f};
#pragma unroll
  for (int m = 0; m < 4; ++m) acc[m] = zero;

  for (int kb = kb0; kb < kb0 + Kc; kb += 128) {
    __syncthreads();
#pragma unroll
    for (int g = 0; g < 4; ++g)
      gload_lds16(A + (size_t)r * K + kb + g * 32 + q * 8,
                  As + ((size_t)g * 256 + wave * 64) * 8);
#pragma unroll
    for (int g = 0; g < 4; ++g)
      gload_lds16(Bt + (size_t)(n0 + r) * K + kb + g * 32 + q * 8,
                  Bs + ((size_t)g * 256 + wave * 64) * 8);
    __syncthreads();

#pragma unroll
    for (int ks = 0; ks < 4; ++ks) {
      s16x8 bfr = *(const s16x8*)&Bs[(ks * 64 + wave * 16 + l15) * 32 + h * 8];
#pragma unroll
      for (int m = 0; m < 4; ++m) {
        s16x8 af = *(const s16x8*)&As[(ks * 64 + m * 16 + l15) * 32 + h * 8];
        acc[m] = __builtin_amdgcn_mfma_f32_16x16x32_bf16(af, bfr, acc[m], 0, 0, 0);
      }
    }
  }

  float* pout = pbuf + (size_t)(blockIdx.y * 64) * N;
#pragma unroll
  for (int m = 0; m < 4; ++m)
#pragma unroll
    for (int j = 0; j < 4; ++j) {
      int row = m * 16 + h * 4 + j;
      int col = n0 + wave * 16 + l15;
      pout[(size_t)row * N + col] = acc[m][j];
    }
}

// ---------------- skinny reduce: out[64][N] = sum_sk partial + bias (+epilogue) ----------------
// EPI: 0 = store; 1 = relu; 2 = +resid
template<int SK, int EPI>
__global__ __launch_bounds__(256) void skinny_reduce(const float* __restrict__ pbuf,
    const float* __restrict__ bias, const float* __restrict__ resid,
    float* __restrict__ outf, bf16* __restrict__ outb, int N)
{
  int s = blockIdx.y, n = blockIdx.x * 256 + threadIdx.x;
  float v = bias[n];
#pragma unroll
  for (int sk = 0; sk < SK; ++sk) v += pbuf[(size_t)(sk * 64 + s) * N + n];
  if (EPI == 1) v = fmaxf(v, 0.f);
  if (EPI == 2) v += resid[(size_t)s * N + n];
  if (outf) outf[(size_t)s * N + n] = v;
  if (outb) outb[(size_t)s * N + n] = f2b(v);
}

// ---------------- fused GRU reduce ----------------
template<int SK>
__global__ __launch_bounds__(256) void gru_reduce(const float* __restrict__ pA,
    const float* __restrict__ pB, const float* __restrict__ bi,
    const float* __restrict__ bh, const float* __restrict__ hprev,
    float* __restrict__ slots)
{
  int s = blockIdx.y, d = blockIdx.x * 256 + threadIdx.x;
  float ir = bi[d], iz = bi[1024 + d], in_ = bi[2048 + d];
  float hr = bh[d], hz = bh[1024 + d], hn = bh[2048 + d];
#pragma unroll
  for (int sk = 0; sk < SK; ++sk) {
    const float* a = pA + (size_t)(sk * 64 + s) * TD;
    const float* b = pB + (size_t)(sk * 64 + s) * TD;
    ir += a[d]; iz += a[1024 + d]; in_ += a[2048 + d];
    hr += b[d]; hz += b[1024 + d]; hn += b[2048 + d];
  }
  float r = 1.f / (1.f + expf(-(ir + hr)));
  float z = 1.f / (1.f + expf(-(iz + hz)));
  float nn = tanhf(in_ + r * hn);
  float h = hprev[(size_t)s * DD + d];
  slots[(size_t)s * DD + d] = (1.f - z) * nn + z * h;
}

// ---------------- fused QK^T + softmax(axis=slots) + colsum ----------------
// grid 256: block computes dots[64 slots][64 dets], softmax over slots in-register,
// writes attn bf16 [s][n] (stride N_DET) + atomic colsum[s].
__global__ __launch_bounds__(256) void qk_softmax(const bf16* __restrict__ qb,
    const bf16* __restrict__ kb, bf16* __restrict__ attn, float* __restrict__ colsum)
{
  __shared__ bf16 Qs[64*64];
  __shared__ bf16 Ks[64*64];
  __shared__ float cs[64];
  const int t = threadIdx.x, lane = t & 63, wave = t >> 6;
  const int n0 = blockIdx.x * 64;
  const int l15 = lane & 15, h = lane >> 4;
  if (t < 64) cs[t] = 0.f;

  f32x4 acc[4];
  const f32x4 zero = {0.f, 0.f, 0.f, 0.f};
#pragma unroll
  for (int m = 0; m < 4; ++m) acc[m] = zero;

  for (int k0 = 0; k0 < DD; k0 += 64) {
    __syncthreads();
#pragma unroll
    for (int c = 0; c < 2; ++c) {
      int i = c * 256 + t;
      int r = i >> 3, q8 = i & 7;
      gload_lds16(qb + (size_t)r * DD + k0 + q8 * 8, Qs + ((size_t)c * 256 + wave * 64) * 8);
    }
#pragma unroll
    for (int c = 0; c < 2; ++c) {
      int i = c * 256 + t;
      int r = i >> 3, q8 = i & 7;
      gload_lds16(kb + (size_t)(n0 + r) * DD + k0 + q8 * 8, Ks + ((size_t)c * 256 + wave * 64) * 8);
    }
    __syncthreads();

#pragma unroll
    for (int ks = 0; ks < 2; ++ks) {
      s16x8 bfr = *(const s16x8*)&Ks[(wave * 16 + l15) * 64 + ks * 32 + h * 8];
#pragma unroll
      for (int m = 0; m < 4; ++m) {
        s16x8 af = *(const s16x8*)&Qs[(m * 16 + l15) * 64 + ks * 32 + h * 8];
        acc[m] = __builtin_amdgcn_mfma_f32_16x16x32_bf16(af, bfr, acc[m], 0, 0, 0);
      }
    }
  }

  // lane holds 16 slot-values for column n = n0 + wave*16 + l15; slots s = m*16 + h*4 + j
  float e[4][4];
  float cmax = -1e30f;
#pragma unroll
  for (int m = 0; m < 4; ++m)
#pragma unroll
    for (int j = 0; j < 4; ++j) { e[m][j] = acc[m][j] * 0.03125f; cmax = fmaxf(cmax, e[m][j]); }
  cmax = fmaxf(cmax, __shfl_xor(cmax, 16, 64));
  cmax = fmaxf(cmax, __shfl_xor(cmax, 32, 64));
  float ssum = 0.f;
#pragma unroll
  for (int m = 0; m < 4; ++m)
#pragma unroll
    for (int j = 0; j < 4; ++j) { e[m][j] = expf(e[m][j] - cmax); ssum += e[m][j]; }
  ssum += __shfl_xor(ssum, 16, 64);
  ssum += __shfl_xor(ssum, 32, 64);
  float inv = 1.f / ssum;
  __syncthreads();   // cs init + LDS reuse safety

  const int n = n0 + wave * 16 + l15;
#pragma unroll
  for (int m = 0; m < 4; ++m)
#pragma unroll
    for (int j = 0; j < 4; ++j) {
      float a = e[m][j] * inv;
      int s = m * 16 + h * 4 + j;
      attn[(size_t)s * N_DET + n] = f2b(a);
      // reduce a over l15 (16 n-values) then one LDS atomic per (s, wave)
      float v = a;
      v += __shfl_xor(v, 1, 64);
      v += __shfl_xor(v, 2, 64);
      v += __shfl_xor(v, 4, 64);
      v += __shfl_xor(v, 8, 64);
      if (l15 == 0) atomicAdd(&cs[s], v);
    }
  __syncthreads();
  if (t < 64) atomicAdd(&colsum[t], cs[t]);
}

// ---------------- updates reduce: upd = (sum_sk partials) / colsum -> bf16 ----------------
template<int SK>
__global__ __launch_bounds__(256) void updates_reduce2(const float* __restrict__ pbuf,
    const float* __restrict__ colsum, bf16* __restrict__ updb)
{
  int s = blockIdx.y, d = blockIdx.x * 256 + threadIdx.x;
  float v = 0.f;
#pragma unroll
  for (int sk = 0; sk < SK; ++sk) v += pbuf[(size_t)(sk * 64 + s) * DD + d];
  updb[(size_t)s * DD + d] = f2b(v / (colsum[s] + 1e-8f));
}

// ---------------- weight transpose+convert: W[K][N] f32 -> Wt[N][K] bf16 ----------------
__global__ __launch_bounds__(256) void transpose_w(const float* __restrict__ W,
                                                   bf16* __restrict__ Wt, int K, int N)
{
  __shared__ float t[32][33];
  int n0 = blockIdx.x * 32, k0 = blockIdx.y * 32;
  int tx = threadIdx.x & 31, ty = threadIdx.x >> 5;
  for (int r = ty; r < 32; r += 8)
    t[r][tx] = W[(size_t)(k0 + r) * N + n0 + tx];
  __syncthreads();
  for (int r = ty; r < 32; r += 8)
    Wt[(size_t)(n0 + r) * K + k0 + tx] = f2b(t[tx][r]);
}

__global__ void f32_to_bf16_v(const float* __restrict__ in, bf16* __restrict__ out, int n)
{
  int i = (blockIdx.x * 256 + threadIdx.x) * 4;
  if (i < n) {
    float4 v = *(const float4*)(in + i);
    bf16 o[4] = {f2b(v.x), f2b(v.y), f2b(v.z), f2b(v.w)};
    *(ushort4*)(out + i) = *(const ushort4*)o;
  }
}

// ---------------- layernorm over rows of [R, 1024] -> bf16 ----------------
template<typename TI>
__global__ __launch_bounds__(256) void ln_rows(const TI* __restrict__ in, bf16* __restrict__ out)
{
  int r = blockIdx.x;
  const TI* p = in + (size_t)r * DD;
  float v[4], s = 0.f, sq = 0.f;
#pragma unroll
  for (int j = 0; j < 4; j++) {
    float x;
    if constexpr (std::is_same<TI, bf16>::value) x = b2f(p[threadIdx.x + j*256]);
    else x = p[threadIdx.x + j*256];
    v[j] = x; s += x; sq += x * x;
  }
  for (int o = 32; o > 0; o >>= 1) { s += __shfl_down(s, o, 64); sq += __shfl_down(sq, o, 64); }
  __shared__ float ls[4], lq[4];
  int w = threadIdx.x >> 6;
  if ((threadIdx.x & 63) == 0) { ls[w] = s; lq[w] = sq; }
  __syncthreads();
  s  = ls[0] + ls[1] + ls[2] + ls[3];
  sq = lq[0] + lq[1] + lq[2] + lq[3];
  float mu = s * (1.f / DD);
  float var = sq * (1.f / DD) - mu * mu;
  float rstd = rsqrtf(var + 1e-5f);
#pragma unroll
  for (int j = 0; j < 4; j++)
    out[(size_t)r*DD + threadIdx.x + j*256] = f2b((v[j] - mu) * rstd);
}

// ---------------- misc ----------------
__global__ void slots_init_k(const float* __restrict__ mu, const float* __restrict__ noise,
                             float* __restrict__ slots)
{
  int gid = blockIdx.x * 256 + threadIdx.x;
  int d = gid & 1023;
  slots[gid] = mu[d] + noise[gid];
}

__global__ void copy_slots_k(const float* __restrict__ in, float* __restrict__ outf,
                             bf16* __restrict__ outb)
{
  int gid = blockIdx.x * 256 + threadIdx.x;
  float v = in[gid];
  outf[gid] = v;
  outb[gid] = f2b(v);
}

__global__ __launch_bounds__(256) void rownorm(const float* __restrict__ in, float* __restrict__ out)
{
  int r = blockIdx.x;
  const float* p = in + (size_t)r * DD;
  float v[4], sq = 0.f;
#pragma unroll
  for (int j = 0; j < 4; j++) { v[j] = p[threadIdx.x + j*256]; sq += v[j]*v[j]; }
  for (int o = 32; o > 0; o >>= 1) sq += __shfl_down(sq, o, 64);
  __shared__ float lq[4];
  int w = threadIdx.x >> 6;
  if ((threadIdx.x & 63) == 0) lq[w] = sq;
  __syncthreads();
  sq = lq[0] + lq[1] + lq[2] + lq[3];
  float sc = 1.f / (sqrtf(sq) + 1e-8f);
#pragma unroll
  for (int j = 0; j < 4; j++) out[(size_t)r*DD + threadIdx.x + j*256] = v[j] * sc;
}

__global__ __launch_bounds__(256) void sim_kernel(const float* __restrict__ an,
    const float* __restrict__ bn, float* __restrict__ simout)
{
  __shared__ float ar[1024];
  int i = blockIdx.x;
  for (int l = threadIdx.x; l < 1024; l += 256) ar[l] = an[(size_t)i * DD + l];
  __syncthreads();
  int j = threadIdx.x >> 2, g = threadIdx.x & 3;
  float sum = 0.f;
  for (int d = g; d < 1024; d += 4) sum += ar[d] * bn[(size_t)j * DD + d];
  sum += __shfl_xor(sum, 1, 64);
  sum += __shfl_xor(sum, 2, 64);
  if (g == 0) simout[i * 64 + j] = sum;
}

__global__ void match_kernel(const float* __restrict__ sim, float* __restrict__ outm)
{
  __shared__ float m[64];
  __shared__ int idx[64];
  __shared__ int order[64];
  __shared__ int used[64];
  int i = threadIdx.x;
  float best = -1e30f; int bj = 0;
  for (int j = 0; j < 64; j++) {
    float v = sim[i * 64 + j];
    if (v > best) { best = v; bj = j; }
  }
  m[i] = best; idx[i] = bj; used[i] = 0;
  __syncthreads();
  int cnt = 0;
  for (int j = 0; j < 64; j++) {
    float mj = m[j];
    if (mj > best || (mj == best && j < i)) cnt++;
  }
  order[cnt] = i;
  __syncthreads();
  if (i == 0) {
    for (int r = 0; r < 64; r++) {
      int ii = order[r];
      int j = idx[ii];
      bool ok = (!used[j]) && (m[ii] > 0.3f);
      outm[ii] = ok ? (float)j : -1.0f;
      if (ok) used[j] = 1;
    }
  }
}

// ---------------- workspace layout (bytes) ----------------
static constexpr size_t OFF_ATT  = 0;                     // attn bf16 [64][16384] 2MB (iter phase)
static constexpr size_t OFF_PA   = (size_t)8  << 20;      // partials A 6MB
static constexpr size_t OFF_PB2  = (size_t)14 << 20;      // partials B 6MB
static constexpr size_t OFF_XPRE = 0;                     // x_pre bf16 32MB (frame stage, aliases above)
static constexpr size_t OFF_WET  = (size_t)32 << 20;
static constexpr size_t OFF_WKT  = OFF_WET + ((size_t)512 << 10);
static constexpr size_t OFF_WVT  = OFF_WKT + ((size_t)2 << 20);
static constexpr size_t OFF_WQT  = OFF_WVT + ((size_t)2 << 20);
static constexpr size_t OFF_W1T  = OFF_WQT + ((size_t)2 << 20);
static constexpr size_t OFF_W2T  = OFF_W1T + ((size_t)4 << 20);
static constexpr size_t OFF_WIB  = OFF_W2T + ((size_t)4 << 20);
static constexpr size_t OFF_WHB  = OFF_WIB + ((size_t)6 << 20);   // ends 58.5MB
static constexpr size_t OFF_X    = (size_t)60 << 20;
static constexpr size_t OFF_DBF  = OFF_X;                          // alias (dead before x write)
static constexpr size_t OFF_K    = OFF_X + ((size_t)32 << 20);
static constexpr size_t OFF_VT   = OFF_K + ((size_t)32 << 20);     // vT bf16 [1024][16384]
static constexpr size_t OFF_SM   = OFF_VT + ((size_t)32 << 20);
static constexpr size_t OFF_SL   = OFF_SM;
static constexpr size_t OFF_SLP  = OFF_SL  + 262144;
static constexpr size_t OFF_SLPB = OFF_SLP + 262144;
static constexpr size_t OFF_PRV  = OFF_SLPB+ 262144;
static constexpr size_t OFF_LNB  = OFF_PRV + 262144;
static constexpr size_t OFF_QB   = OFF_LNB + 262144;
static constexpr size_t OFF_UPDB = OFF_QB  + 262144;
static constexpr size_t OFF_HIDB = OFF_UPDB+ 262144;
static constexpr size_t OFF_AN   = OFF_HIDB+ 262144;
static constexpr size_t OFF_BN   = OFF_AN  + 262144;
static constexpr size_t OFF_CS   = OFF_BN  + 262144;

extern "C" void kernel_launch(void* const* d_in, const int* in_sizes, int n_in,
                              void* d_out, int out_size, void* d_ws, size_t ws_size,
                              hipStream_t stream)
{
  (void)in_sizes; (void)n_in; (void)out_size; (void)ws_size;
  const float* dets_t   = (const float*)d_in[0];
  const float* dets_t1  = (const float*)d_in[1];
  const float* W_enc    = (const float*)d_in[2];
  const float* b_enc    = (const float*)d_in[3];
  const float* Wq       = (const float*)d_in[4];
  const float* bq       = (const float*)d_in[5];
  const float* Wk       = (const float*)d_in[6];
  const float* bk       = (const float*)d_in[7];
  const float* Wv       = (const float*)d_in[8];
  const float* bv       = (const float*)d_in[9];
  const float* Wi       = (const float*)d_in[10];
  const float* Wh       = (const float*)d_in[11];
  const float* bi       = (const float*)d_in[12];
  const float* bh       = (const float*)d_in[13];
  const float* W1       = (const float*)d_in[14];
  const float* b1       = (const float*)d_in[15];
  const float* W2       = (const float*)d_in[16];
  const float* b2       = (const float*)d_in[17];
  const float* slots_mu = (const float*)d_in[18];
  const float* init_noise = (const float*)d_in[19];

  char* ws = (char*)d_ws;
  bf16*  x_pre  = (bf16*)(ws + OFF_XPRE);
  bf16*  attn   = (bf16*)(ws + OFF_ATT);
  float* pA     = (float*)(ws + OFF_PA);
  float* pB     = (float*)(ws + OFF_PB2);
  bf16*  Wenc_t = (bf16*)(ws + OFF_WET);
  bf16*  Wk_t   = (bf16*)(ws + OFF_WKT);
  bf16*  Wv_t   = (bf16*)(ws + OFF_WVT);
  bf16*  Wq_t   = (bf16*)(ws + OFF_WQT);
  bf16*  W1_t   = (bf16*)(ws + OFF_W1T);
  bf16*  W2_t   = (bf16*)(ws + OFF_W2T);
  bf16*  Wi_b   = (bf16*)(ws + OFF_WIB);
  bf16*  Wh_b   = (bf16*)(ws + OFF_WHB);
  bf16*  dets_bf= (bf16*)(ws + OFF_DBF);
  bf16*  x      = (bf16*)(ws + OFF_X);
  bf16*  kbuf   = (bf16*)(ws + OFF_K);
  bf16*  vT     = (bf16*)(ws + OFF_VT);
  float* slots  = (float*)(ws + OFF_SL);
  float* slotsp = (float*)(ws + OFF_SLP);
  bf16*  slotspb= (bf16*)(ws + OFF_SLPB);
  float* prevs  = (float*)(ws + OFF_PRV);
  bf16*  lnb    = (bf16*)(ws + OFF_LNB);
  bf16*  qb     = (bf16*)(ws + OFF_QB);
  bf16*  updb   = (bf16*)(ws + OFF_UPDB);
  bf16*  hidb   = (bf16*)(ws + OFF_HIDB);
  float* an     = (float*)(ws + OFF_AN);
  float* bn     = (float*)(ws + OFF_BN);
  float* colsum = (float*)(ws + OFF_CS);

  transpose_w<<<dim3(32,  8), 256, 0, stream>>>(W_enc, Wenc_t, DIN, DD);
  transpose_w<<<dim3(32, 32), 256, 0, stream>>>(Wk,    Wk_t,   DD,  DD);
  transpose_w<<<dim3(32, 32), 256, 0, stream>>>(Wv,    Wv_t,   DD,  DD);
  transpose_w<<<dim3(32, 32), 256, 0, stream>>>(Wq,    Wq_t,   DD,  DD);
  transpose_w<<<dim3(64, 32), 256, 0, stream>>>(W1,    W1_t,   DD,  HH);
  transpose_w<<<dim3(32, 64), 256, 0, stream>>>(W2,    W2_t,   HH,  DD);
  f32_to_bf16_v<<<(TD*DD)/1024, 256, 0, stream>>>(Wi, Wi_b, TD*DD);
  f32_to_bf16_v<<<(TD*DD)/1024, 256, 0, stream>>>(Wh, Wh_b, TD*DD);

  auto frame = [&](const float* dets, bool first) {
    f32_to_bf16_v<<<(N_DET*DIN)/1024, 256, 0, stream>>>(dets, dets_bf, N_DET*DIN);
    gemm_mfma_bt<bf16, false><<<dim3(8, 128), 256, 0, stream>>>(dets_bf, Wenc_t, b_enc, x_pre, N_DET, DD, DIN);
    ln_rows<bf16><<<N_DET, 256, 0, stream>>>(x_pre, x);
    gemm_mfma_bt<bf16, false><<<dim3(8, 128), 256, 0, stream>>>(x, Wk_t, bk, kbuf, N_DET, DD, DD);
    gemm_mfma_bt<bf16, true ><<<dim3(8, 128), 256, 0, stream>>>(x, Wv_t, bv, vT,   N_DET, DD, DD);
    if (first) slots_init_k<<<256, 256, 0, stream>>>(slots_mu, init_noise, slots);
    for (int it = 0; it < 3; ++it) {
      copy_slots_k<<<256, 256, 0, stream>>>(slots, slotsp, slotspb);
      ln_rows<float><<<KSLOT, 256, 0, stream>>>(slots, lnb);
      gemm_skinny_loop<<<dim3(16, 8), 256, 0, stream>>>(lnb, Wq_t, pA, DD, DD, 128);
      skinny_reduce<8, 0><<<dim3(4, 64), 256, 0, stream>>>(pA, bq, nullptr, nullptr, qb, DD);
      hipMemsetAsync(colsum, 0, 256, stream);
      qk_softmax<<<256, 256, 0, stream>>>(qb, kbuf, attn, colsum);
      gemm_skinny_loop<<<dim3(16, 8), 256, 0, stream>>>(attn, vT, pA, DD, N_DET, 2048);
      updates_reduce2<8><<<dim3(4, 64), 256, 0, stream>>>(pA, colsum, updb);
      gemm_skinny_loop<<<dim3(48, 8), 256, 0, stream>>>(updb,    Wi_b, pA, TD, DD, 128);
      gemm_skinny_loop<<<dim3(48, 8), 256, 0, stream>>>(slotspb, Wh_b, pB, TD, DD, 128);
      gru_reduce<8><<<dim3(4, 64), 256, 0, stream>>>(pA, pB, bi, bh, slotsp, slots);
      ln_rows<float><<<KSLOT, 256, 0, stream>>>(slots, lnb);
      gemm_skinny_loop<<<dim3(32, 8), 256, 0, stream>>>(lnb, W1_t, pA, HH, DD, 128);
      skinny_reduce<8, 1><<<dim3(8, 64), 256, 0, stream>>>(pA, b1, nullptr, nullptr, hidb, HH);
      gemm_skinny_loop<<<dim3(16, 16), 256, 0, stream>>>(hidb, W2_t, pA, DD, HH, 128);
      skinny_reduce<16, 2><<<dim3(4, 64), 256, 0, stream>>>(pA, b2, slots, slots, nullptr, DD);
    }
  };

  frame(dets_t, true);
  hipMemcpyAsync(prevs, slots, 262144, hipMemcpyDeviceToDevice, stream);
  frame(dets_t1, false);

  rownorm<<<KSLOT, 256, 0, stream>>>(prevs, an);
  rownorm<<<KSLOT, 256, 0, stream>>>(slots, bn);
  float* outf = (float*)d_out;
  sim_kernel<<<KSLOT, 256, 0, stream>>>(an, bn, outf + 64);
  match_kernel<<<1, 64, 0, stream>>>(outf + 64, outf);
}

// Round 5
// 835.899 us; speedup vs baseline: 12.6122x; 1.0749x over previous
//
#include <hip/hip_runtime.h>
#include <hip/hip_bf16.h>
#include <type_traits>

typedef __hip_bfloat16 bf16;
typedef __attribute__((ext_vector_type(8))) short s16x8;   // 8 bf16 (4 VGPRs)
typedef __attribute__((ext_vector_type(4))) float f32x4;

#define N_DET 16384
#define DIN   256
#define DD    1024
#define KSLOT 64
#define HH    2048
#define TD    3072

__device__ __forceinline__ float b2f(bf16 x){ return __bfloat162float(x); }
__device__ __forceinline__ bf16  f2b(float x){ return __float2bfloat16(x); }

__device__ __forceinline__ void gload_lds16(const void* g, void* l) {
  __builtin_amdgcn_global_load_lds(
      (const __attribute__((address_space(1))) unsigned int*)g,
      (__attribute__((address_space(3))) unsigned int*)l, 16, 0, 0);
}

// ---------------- MFMA GEMM: C[M,N] = A[M,K] @ Bt[N,K]^T + bias ----------------
// 1D grid (M/128)*(N/128); N must be 1024 (8 col tiles). XCD-swizzled (T1):
// each XCD gets a contiguous chunk of row-panels -> A fetched once chip-wide.
// TR=false: C[row*N+col]. TR=true: C^T stored as C[col*M+row] (bf16, packed 4-row stores)
template<typename TO, bool TR>
__global__ __launch_bounds__(256) void gemm_mfma_bt(
    const bf16* __restrict__ A, const bf16* __restrict__ Bt,
    const float* __restrict__ bias, TO* __restrict__ C, int M, int N, int K)
{
  const int chunk = gridDim.x >> 3;               // gridDim.x % 8 == 0
  const int wg = (blockIdx.x & 7) * chunk + (blockIdx.x >> 3);
  const int bn = (wg & 7) * 128;                  // col tile fastest within chunk
  const int bm = (wg >> 3) * 128;

  __shared__ bf16 As[128*32];
  __shared__ bf16 Bs[128*32];
  const int lane = threadIdx.x & 63, wave = threadIdx.x >> 6;
  const int wr = wave >> 1, wc = wave & 1;

  f32x4 acc[4][4];
  const f32x4 zero = {0.f, 0.f, 0.f, 0.f};
#pragma unroll
  for (int m = 0; m < 4; ++m)
#pragma unroll
    for (int n = 0; n < 4; ++n) acc[m][n] = zero;

  for (int k0 = 0; k0 < K; k0 += 32) {
    __syncthreads();
#pragma unroll
    for (int c = 0; c < 2; ++c) {
      int i = wave * 64 + c * 256 + lane;
      int r = i >> 2, q = i & 3;
      gload_lds16(A + (size_t)(bm + r) * K + k0 + q * 8,
                  As + (size_t)(wave * 64 + c * 256) * 8);
    }
#pragma unroll
    for (int c = 0; c < 2; ++c) {
      int i = wave * 64 + c * 256 + lane;
      int r = i >> 2, q = i & 3;
      gload_lds16(Bt + (size_t)(bn + r) * K + k0 + q * 8,
                  Bs + (size_t)(wave * 64 + c * 256) * 8);
    }
    __syncthreads();

    s16x8 af[4], bfr[4];
#pragma unroll
    for (int m = 0; m < 4; ++m)
      af[m] = *(const s16x8*)&As[(wr * 64 + m * 16 + (lane & 15)) * 32 + (lane >> 4) * 8];
#pragma unroll
    for (int n = 0; n < 4; ++n)
      bfr[n] = *(const s16x8*)&Bs[(wc * 64 + n * 16 + (lane & 15)) * 32 + (lane >> 4) * 8];
#pragma unroll
    for (int m = 0; m < 4; ++m)
#pragma unroll
      for (int n = 0; n < 4; ++n)
        acc[m][n] = __builtin_amdgcn_mfma_f32_16x16x32_bf16(af[m], bfr[n], acc[m][n], 0, 0, 0);
  }

#pragma unroll
  for (int m = 0; m < 4; ++m)
#pragma unroll
    for (int n = 0; n < 4; ++n) {
      int col = bn + wc * 64 + n * 16 + (lane & 15);
      float bv = bias[col];
      if constexpr (TR) {
        int row0 = bm + wr * 64 + m * 16 + (lane >> 4) * 4;
        bf16 pk[4];
#pragma unroll
        for (int j = 0; j < 4; ++j) pk[j] = f2b(acc[m][n][j] + bv);
        *(ushort4*)((bf16*)C + (size_t)col * M + row0) = *(const ushort4*)pk;
      } else {
#pragma unroll
        for (int j = 0; j < 4; ++j) {
          int row = bm + wr * 64 + m * 16 + (lane >> 4) * 4 + j;
          float v = acc[m][n][j] + bv;
          if constexpr (std::is_same<TO, bf16>::value)
            C[(size_t)row * N + col] = f2b(v);
          else
            C[(size_t)row * N + col] = v;
        }
      }
    }
}

// ---------------- skinny split-K MFMA body: partial[orow..][64][N] = A[64,Kc]@Bt[N,Kc]^T ----------------
__device__ __forceinline__ void skinny_body(bf16* As, bf16* Bs,
    const bf16* __restrict__ A, const bf16* __restrict__ Bt,
    float* __restrict__ pbuf, int N, int K, int Kc, int n0, int kb0, int orow, int tid)
{
  const int lane = tid & 63, wave = tid >> 6;
  const int rem = wave * 64 + lane;
  const int r = rem >> 2, q = rem & 3;
  const int l15 = lane & 15, h = lane >> 4;

  f32x4 acc[4];
  const f32x4 zero = {0.f, 0.f, 0.f, 0.f};
#pragma unroll
  for (int m = 0; m < 4; ++m) acc[m] = zero;

  for (int kb = kb0; kb < kb0 + Kc; kb += 128) {
    __syncthreads();
#pragma unroll
    for (int g = 0; g < 4; ++g)
      gload_lds16(A + (size_t)r * K + kb + g * 32 + q * 8,
                  As + ((size_t)g * 256 + wave * 64) * 8);
#pragma unroll
    for (int g = 0; g < 4; ++g)
      gload_lds16(Bt + (size_t)(n0 + r) * K + kb + g * 32 + q * 8,
                  Bs + ((size_t)g * 256 + wave * 64) * 8);
    __syncthreads();

#pragma unroll
    for (int ks = 0; ks < 4; ++ks) {
      s16x8 bfr = *(const s16x8*)&Bs[(ks * 64 + wave * 16 + l15) * 32 + h * 8];
#pragma unroll
      for (int m = 0; m < 4; ++m) {
        s16x8 af = *(const s16x8*)&As[(ks * 64 + m * 16 + l15) * 32 + h * 8];
        acc[m] = __builtin_amdgcn_mfma_f32_16x16x32_bf16(af, bfr, acc[m], 0, 0, 0);
      }
    }
  }

  float* pout = pbuf + (size_t)orow * N;
#pragma unroll
  for (int m = 0; m < 4; ++m)
#pragma unroll
    for (int j = 0; j < 4; ++j) {
      int row = m * 16 + h * 4 + j;
      int col = n0 + wave * 16 + l15;
      pout[(size_t)row * N + col] = acc[m][j];
    }
}

__global__ __launch_bounds__(256) void gemm_skinny_loop(
    const bf16* __restrict__ A, const bf16* __restrict__ Bt,
    float* __restrict__ pbuf, int N, int K, int Kc)
{
  __shared__ bf16 As[4*64*32];
  __shared__ bf16 Bs[4*64*32];
  skinny_body(As, Bs, A, Bt, pbuf, N, K, Kc,
              blockIdx.x * 64, blockIdx.y * Kc, blockIdx.y * 64, threadIdx.x);
}

// dual: z=0 -> A0@B0 -> p0, z=1 -> A1@B1 -> p1 (Wi/Wh pair in one launch)
__global__ __launch_bounds__(256) void gemm_skinny_dual(
    const bf16* __restrict__ A0, const bf16* __restrict__ A1,
    const bf16* __restrict__ B0, const bf16* __restrict__ B1,
    float* __restrict__ p0, float* __restrict__ p1, int N, int K, int Kc)
{
  __shared__ bf16 As[4*64*32];
  __shared__ bf16 Bs[4*64*32];
  if (blockIdx.z == 0)
    skinny_body(As, Bs, A0, B0, p0, N, K, Kc,
                blockIdx.x * 64, blockIdx.y * Kc, blockIdx.y * 64, threadIdx.x);
  else
    skinny_body(As, Bs, A1, B1, p1, N, K, Kc,
                blockIdx.x * 64, blockIdx.y * Kc, blockIdx.y * 64, threadIdx.x);
}

// ---------------- reduce_q: qb = sum partials + bq; also zeroes colsum ----------------
__global__ __launch_bounds__(256) void reduce_q(const float* __restrict__ pbuf,
    const float* __restrict__ bias, bf16* __restrict__ qb, float* __restrict__ colsum)
{
  int s = blockIdx.y, n = blockIdx.x * 256 + threadIdx.x;
  float v = bias[n];
#pragma unroll
  for (int sk = 0; sk < 8; ++sk) v += pbuf[(size_t)(sk * 64 + s) * DD + n];
  qb[(size_t)s * DD + n] = f2b(v);
  if (blockIdx.x == 0 && blockIdx.y == 0 && threadIdx.x < 64) colsum[threadIdx.x] = 0.f;
}

// ---------------- skinny reduce (EPI 1 = relu -> bf16) ----------------
template<int SK, int EPI>
__global__ __launch_bounds__(256) void skinny_reduce(const float* __restrict__ pbuf,
    const float* __restrict__ bias, const float* __restrict__ resid,
    float* __restrict__ outf, bf16* __restrict__ outb, int N)
{
  int s = blockIdx.y, n = blockIdx.x * 256 + threadIdx.x;
  float v = bias[n];
#pragma unroll
  for (int sk = 0; sk < SK; ++sk) v += pbuf[(size_t)(sk * 64 + s) * N + n];
  if (EPI == 1) v = fmaxf(v, 0.f);
  if (EPI == 2) v += resid[(size_t)s * N + n];
  if (outf) outf[(size_t)s * N + n] = v;
  if (outb) outb[(size_t)s * N + n] = f2b(v);
}

// ---------------- block LN helper (256 thr, 1024 elems, vals in v[4]) ----------------
__device__ __forceinline__ void block_ln_store(float v[4], float s, float sq,
                                               bf16* __restrict__ out, int row)
{
  for (int o = 32; o > 0; o >>= 1) { s += __shfl_down(s, o, 64); sq += __shfl_down(sq, o, 64); }
  __shared__ float ls[4], lq[4];
  int w = threadIdx.x >> 6;
  if ((threadIdx.x & 63) == 0) { ls[w] = s; lq[w] = sq; }
  __syncthreads();
  s  = ls[0] + ls[1] + ls[2] + ls[3];
  sq = lq[0] + lq[1] + lq[2] + lq[3];
  float mu = s * (1.f / DD);
  float var = sq * (1.f / DD) - mu * mu;
  float rstd = rsqrtf(var + 1e-5f);
#pragma unroll
  for (int j = 0; j < 4; j++)
    out[(size_t)row * DD + threadIdx.x + j * 256] = f2b((v[j] - mu) * rstd);
}

// ---------------- fused GRU reduce + LN: slots = gru(...), lnb = LN(slots) ----------------
__global__ __launch_bounds__(256) void gru_reduce_ln(const float* __restrict__ pA,
    const float* __restrict__ pB, const float* __restrict__ bi,
    const float* __restrict__ bh, float* __restrict__ slots, bf16* __restrict__ lnb)
{
  int s = blockIdx.x, t = threadIdx.x;
  float v[4], sum = 0.f, sq = 0.f;
#pragma unroll
  for (int j = 0; j < 4; ++j) {
    int d = t + j * 256;
    float ir = bi[d], iz = bi[1024 + d], in_ = bi[2048 + d];
    float hr = bh[d], hz = bh[1024 + d], hnn = bh[2048 + d];
#pragma unroll
    for (int sk = 0; sk < 8; ++sk) {
      const float* a = pA + (size_t)(sk * 64 + s) * TD;
      const float* b = pB + (size_t)(sk * 64 + s) * TD;
      ir += a[d]; iz += a[1024 + d]; in_ += a[2048 + d];
      hr += b[d]; hz += b[1024 + d]; hnn += b[2048 + d];
    }
    float r = 1.f / (1.f + expf(-(ir + hr)));
    float z = 1.f / (1.f + expf(-(iz + hz)));
    float nn = tanhf(in_ + r * hnn);
    float h = slots[(size_t)s * DD + d];
    float hv = (1.f - z) * nn + z * h;
    slots[(size_t)s * DD + d] = hv;
    v[j] = hv; sum += hv; sq += hv * hv;
  }
  block_ln_store(v, sum, sq, lnb, s);
}

// ---------------- fused MLP-out reduce + resid + LN + bf16 prev-copy ----------------
// slots += mlp_out; slotspb = bf16(slots) (next iter's prev); lnb = LN(slots) (next iter's q input)
__global__ __launch_bounds__(256) void mlp2_reduce_ln(const float* __restrict__ pbuf,
    const float* __restrict__ bias, float* __restrict__ slots,
    bf16* __restrict__ slotspb, bf16* __restrict__ lnb)
{
  int s = blockIdx.x, t = threadIdx.x;
  float v[4], sum = 0.f, sq = 0.f;
#pragma unroll
  for (int j = 0; j < 4; ++j) {
    int d = t + j * 256;
    float x = bias[d] + slots[(size_t)s * DD + d];
#pragma unroll
    for (int sk = 0; sk < 16; ++sk) x += pbuf[(size_t)(sk * 64 + s) * DD + d];
    slots[(size_t)s * DD + d] = x;
    slotspb[(size_t)s * DD + d] = f2b(x);
    v[j] = x; sum += x; sq += x * x;
  }
  block_ln_store(v, sum, sq, lnb, s);
}

// ---------------- slots init (frame 1) / prep (frame 2): slots, slotspb, lnb ----------------
__global__ __launch_bounds__(256) void slots_init_ln(const float* __restrict__ mu,
    const float* __restrict__ noise, float* __restrict__ slots,
    bf16* __restrict__ slotspb, bf16* __restrict__ lnb)
{
  int s = blockIdx.x, t = threadIdx.x;
  float v[4], sum = 0.f, sq = 0.f;
#pragma unroll
  for (int j = 0; j < 4; ++j) {
    int d = t + j * 256;
    float x = mu[d] + noise[(size_t)s * DD + d];
    slots[(size_t)s * DD + d] = x;
    slotspb[(size_t)s * DD + d] = f2b(x);
    v[j] = x; sum += x; sq += x * x;
  }
  block_ln_store(v, sum, sq, lnb, s);
}

__global__ __launch_bounds__(256) void prep_ln(const float* __restrict__ slots,
    bf16* __restrict__ slotspb, bf16* __restrict__ lnb)
{
  int s = blockIdx.x, t = threadIdx.x;
  float v[4], sum = 0.f, sq = 0.f;
#pragma unroll
  for (int j = 0; j < 4; ++j) {
    int d = t + j * 256;
    float x = slots[(size_t)s * DD + d];
    slotspb[(size_t)s * DD + d] = f2b(x);
    v[j] = x; sum += x; sq += x * x;
  }
  block_ln_store(v, sum, sq, lnb, s);
}

// ---------------- fused QK^T + softmax(axis=slots) + colsum ----------------
__global__ __launch_bounds__(256) void qk_softmax(const bf16* __restrict__ qb,
    const bf16* __restrict__ kb, bf16* __restrict__ attn, float* __restrict__ colsum)
{
  __shared__ bf16 Qs[64*64];
  __shared__ bf16 Ks[64*64];
  __shared__ float cs[64];
  const int t = threadIdx.x, lane = t & 63, wave = t >> 6;
  const int n0 = blockIdx.x * 64;
  const int l15 = lane & 15, h = lane >> 4;
  if (t < 64) cs[t] = 0.f;

  f32x4 acc[4];
  const f32x4 zero = {0.f, 0.f, 0.f, 0.f};
#pragma unroll
  for (int m = 0; m < 4; ++m) acc[m] = zero;

  for (int k0 = 0; k0 < DD; k0 += 64) {
    __syncthreads();
#pragma unroll
    for (int c = 0; c < 2; ++c) {
      int i = c * 256 + t;
      int r = i >> 3, q8 = i & 7;
      gload_lds16(qb + (size_t)r * DD + k0 + q8 * 8, Qs + ((size_t)c * 256 + wave * 64) * 8);
    }
#pragma unroll
    for (int c = 0; c < 2; ++c) {
      int i = c * 256 + t;
      int r = i >> 3, q8 = i & 7;
      gload_lds16(kb + (size_t)(n0 + r) * DD + k0 + q8 * 8, Ks + ((size_t)c * 256 + wave * 64) * 8);
    }
    __syncthreads();

#pragma unroll
    for (int ks = 0; ks < 2; ++ks) {
      s16x8 bfr = *(const s16x8*)&Ks[(wave * 16 + l15) * 64 + ks * 32 + h * 8];
#pragma unroll
      for (int m = 0; m < 4; ++m) {
        s16x8 af = *(const s16x8*)&Qs[(m * 16 + l15) * 64 + ks * 32 + h * 8];
        acc[m] = __builtin_amdgcn_mfma_f32_16x16x32_bf16(af, bfr, acc[m], 0, 0, 0);
      }
    }
  }

  float e[4][4];
  float cmax = -1e30f;
#pragma unroll
  for (int m = 0; m < 4; ++m)
#pragma unroll
    for (int j = 0; j < 4; ++j) { e[m][j] = acc[m][j] * 0.03125f; cmax = fmaxf(cmax, e[m][j]); }
  cmax = fmaxf(cmax, __shfl_xor(cmax, 16, 64));
  cmax = fmaxf(cmax, __shfl_xor(cmax, 32, 64));
  float ssum = 0.f;
#pragma unroll
  for (int m = 0; m < 4; ++m)
#pragma unroll
    for (int j = 0; j < 4; ++j) { e[m][j] = expf(e[m][j] - cmax); ssum += e[m][j]; }
  ssum += __shfl_xor(ssum, 16, 64);
  ssum += __shfl_xor(ssum, 32, 64);
  float inv = 1.f / ssum;
  __syncthreads();

  const int n = n0 + wave * 16 + l15;
#pragma unroll
  for (int m = 0; m < 4; ++m)
#pragma unroll
    for (int j = 0; j < 4; ++j) {
      float a = e[m][j] * inv;
      int s = m * 16 + h * 4 + j;
      attn[(size_t)s * N_DET + n] = f2b(a);
      float v = a;
      v += __shfl_xor(v, 1, 64);
      v += __shfl_xor(v, 2, 64);
      v += __shfl_xor(v, 4, 64);
      v += __shfl_xor(v, 8, 64);
      if (l15 == 0) atomicAdd(&cs[s], v);
    }
  __syncthreads();
  if (t < 64) atomicAdd(&colsum[t], cs[t]);
}

// ---------------- updates reduce: upd = (sum_sk partials) / colsum -> bf16 ----------------
template<int SK>
__global__ __launch_bounds__(256) void updates_reduce2(const float* __restrict__ pbuf,
    const float* __restrict__ colsum, bf16* __restrict__ updb)
{
  int s = blockIdx.y, d = blockIdx.x * 256 + threadIdx.x;
  float v = 0.f;
#pragma unroll
  for (int sk = 0; sk < SK; ++sk) v += pbuf[(size_t)(sk * 64 + s) * DD + d];
  updb[(size_t)s * DD + d] = f2b(v / (colsum[s] + 1e-8f));
}

// ---------------- weight transpose+convert: W[K][N] f32 -> Wt[N][K] bf16 ----------------
__global__ __launch_bounds__(256) void transpose_w(const float* __restrict__ W,
                                                   bf16* __restrict__ Wt, int K, int N)
{
  __shared__ float t[32][33];
  int n0 = blockIdx.x * 32, k0 = blockIdx.y * 32;
  int tx = threadIdx.x & 31, ty = threadIdx.x >> 5;
  for (int r = ty; r < 32; r += 8)
    t[r][tx] = W[(size_t)(k0 + r) * N + n0 + tx];
  __syncthreads();
  for (int r = ty; r < 32; r += 8)
    Wt[(size_t)(n0 + r) * K + k0 + tx] = f2b(t[tx][r]);
}

__global__ void f32_to_bf16_v(const float* __restrict__ in, bf16* __restrict__ out, int n)
{
  int i = (blockIdx.x * 256 + threadIdx.x) * 4;
  if (i < n) {
    float4 v = *(const float4*)(in + i);
    bf16 o[4] = {f2b(v.x), f2b(v.y), f2b(v.z), f2b(v.w)};
    *(ushort4*)(out + i) = *(const ushort4*)o;
  }
}

// ---------------- layernorm over rows of [R, 1024] -> bf16 (x path) ----------------
template<typename TI>
__global__ __launch_bounds__(256) void ln_rows(const TI* __restrict__ in, bf16* __restrict__ out)
{
  int r = blockIdx.x;
  const TI* p = in + (size_t)r * DD;
  float v[4], s = 0.f, sq = 0.f;
#pragma unroll
  for (int j = 0; j < 4; j++) {
    float x;
    if constexpr (std::is_same<TI, bf16>::value) x = b2f(p[threadIdx.x + j*256]);
    else x = p[threadIdx.x + j*256];
    v[j] = x; s += x; sq += x * x;
  }
  block_ln_store(v, s, sq, out, r);
}

// ---------------- finalize ----------------
__global__ __launch_bounds__(256) void rownorm(const float* __restrict__ in, float* __restrict__ out)
{
  int r = blockIdx.x;
  const float* p = in + (size_t)r * DD;
  float v[4], sq = 0.f;
#pragma unroll
  for (int j = 0; j < 4; j++) { v[j] = p[threadIdx.x + j*256]; sq += v[j]*v[j]; }
  for (int o = 32; o > 0; o >>= 1) sq += __shfl_down(sq, o, 64);
  __shared__ float lq[4];
  int w = threadIdx.x >> 6;
  if ((threadIdx.x & 63) == 0) lq[w] = sq;
  __syncthreads();
  sq = lq[0] + lq[1] + lq[2] + lq[3];
  float sc = 1.f / (sqrtf(sq) + 1e-8f);
#pragma unroll
  for (int j = 0; j < 4; j++) out[(size_t)r*DD + threadIdx.x + j*256] = v[j] * sc;
}

__global__ __launch_bounds__(256) void sim_kernel(const float* __restrict__ an,
    const float* __restrict__ bn, float* __restrict__ simout)
{
  __shared__ float ar[1024];
  int i = blockIdx.x;
  for (int l = threadIdx.x; l < 1024; l += 256) ar[l] = an[(size_t)i * DD + l];
  __syncthreads();
  int j = threadIdx.x >> 2, g = threadIdx.x & 3;
  float sum = 0.f;
  for (int d = g; d < 1024; d += 4) sum += ar[d] * bn[(size_t)j * DD + d];
  sum += __shfl_xor(sum, 1, 64);
  sum += __shfl_xor(sum, 2, 64);
  if (g == 0) simout[i * 64 + j] = sum;
}

__global__ void match_kernel(const float* __restrict__ sim, float* __restrict__ outm)
{
  __shared__ float m[64];
  __shared__ int idx[64];
  __shared__ int order[64];
  __shared__ int used[64];
  int i = threadIdx.x;
  float best = -1e30f; int bj = 0;
  for (int j = 0; j < 64; j++) {
    float v = sim[i * 64 + j];
    if (v > best) { best = v; bj = j; }
  }
  m[i] = best; idx[i] = bj; used[i] = 0;
  __syncthreads();
  int cnt = 0;
  for (int j = 0; j < 64; j++) {
    float mj = m[j];
    if (mj > best || (mj == best && j < i)) cnt++;
  }
  order[cnt] = i;
  __syncthreads();
  if (i == 0) {
    for (int r = 0; r < 64; r++) {
      int ii = order[r];
      int j = idx[ii];
      bool ok = (!used[j]) && (m[ii] > 0.3f);
      outm[ii] = ok ? (float)j : -1.0f;
      if (ok) used[j] = 1;
    }
  }
}

// ---------------- workspace layout (bytes) ----------------
static constexpr size_t OFF_ATT  = 0;                     // attn bf16 [64][16384] 2MB (iter phase)
static constexpr size_t OFF_PA   = (size_t)8  << 20;      // partials A 6MB
static constexpr size_t OFF_PB2  = (size_t)14 << 20;      // partials B 6MB
static constexpr size_t OFF_XPRE = 0;                     // x_pre bf16 32MB (frame stage, aliases above)
static constexpr size_t OFF_WET  = (size_t)32 << 20;
static constexpr size_t OFF_WKT  = OFF_WET + ((size_t)512 << 10);
static constexpr size_t OFF_WVT  = OFF_WKT + ((size_t)2 << 20);
static constexpr size_t OFF_WQT  = OFF_WVT + ((size_t)2 << 20);
static constexpr size_t OFF_W1T  = OFF_WQT + ((size_t)2 << 20);
static constexpr size_t OFF_W2T  = OFF_W1T + ((size_t)4 << 20);
static constexpr size_t OFF_WIB  = OFF_W2T + ((size_t)4 << 20);
static constexpr size_t OFF_WHB  = OFF_WIB + ((size_t)6 << 20);   // ends 58.5MB
static constexpr size_t OFF_X    = (size_t)60 << 20;
static constexpr size_t OFF_DBF  = OFF_X;                          // alias (dead before x write)
static constexpr size_t OFF_K    = OFF_X + ((size_t)32 << 20);
static constexpr size_t OFF_VT   = OFF_K + ((size_t)32 << 20);     // vT bf16 [1024][16384]
static constexpr size_t OFF_SM   = OFF_VT + ((size_t)32 << 20);
static constexpr size_t OFF_SL   = OFF_SM;
static constexpr size_t OFF_SLPB = OFF_SL  + 262144;
static constexpr size_t OFF_PRV  = OFF_SLPB+ 262144;
static constexpr size_t OFF_LNB  = OFF_PRV + 262144;
static constexpr size_t OFF_QB   = OFF_LNB + 262144;
static constexpr size_t OFF_UPDB = OFF_QB  + 262144;
static constexpr size_t OFF_HIDB = OFF_UPDB+ 262144;
static constexpr size_t OFF_AN   = OFF_HIDB+ 262144;
static constexpr size_t OFF_BN   = OFF_AN  + 262144;
static constexpr size_t OFF_CS   = OFF_BN  + 262144;

extern "C" void kernel_launch(void* const* d_in, const int* in_sizes, int n_in,
                              void* d_out, int out_size, void* d_ws, size_t ws_size,
                              hipStream_t stream)
{
  (void)in_sizes; (void)n_in; (void)out_size; (void)ws_size;
  const float* dets_t   = (const float*)d_in[0];
  const float* dets_t1  = (const float*)d_in[1];
  const float* W_enc    = (const float*)d_in[2];
  const float* b_enc    = (const float*)d_in[3];
  const float* Wq       = (const float*)d_in[4];
  const float* bq       = (const float*)d_in[5];
  const float* Wk       = (const float*)d_in[6];
  const float* bk       = (const float*)d_in[7];
  const float* Wv       = (const float*)d_in[8];
  const float* bv       = (const float*)d_in[9];
  const float* Wi       = (const float*)d_in[10];
  const float* Wh       = (const float*)d_in[11];
  const float* bi       = (const float*)d_in[12];
  const float* bh       = (const float*)d_in[13];
  const float* W1       = (const float*)d_in[14];
  const float* b1       = (const float*)d_in[15];
  const float* W2       = (const float*)d_in[16];
  const float* b2       = (const float*)d_in[17];
  const float* slots_mu = (const float*)d_in[18];
  const float* init_noise = (const float*)d_in[19];

  char* ws = (char*)d_ws;
  bf16*  x_pre  = (bf16*)(ws + OFF_XPRE);
  bf16*  attn   = (bf16*)(ws + OFF_ATT);
  float* pA     = (float*)(ws + OFF_PA);
  float* pB     = (float*)(ws + OFF_PB2);
  bf16*  Wenc_t = (bf16*)(ws + OFF_WET);
  bf16*  Wk_t   = (bf16*)(ws + OFF_WKT);
  bf16*  Wv_t   = (bf16*)(ws + OFF_WVT);
  bf16*  Wq_t   = (bf16*)(ws + OFF_WQT);
  bf16*  W1_t   = (bf16*)(ws + OFF_W1T);
  bf16*  W2_t   = (bf16*)(ws + OFF_W2T);
  bf16*  Wi_b   = (bf16*)(ws + OFF_WIB);
  bf16*  Wh_b   = (bf16*)(ws + OFF_WHB);
  bf16*  dets_bf= (bf16*)(ws + OFF_DBF);
  bf16*  x      = (bf16*)(ws + OFF_X);
  bf16*  kbuf   = (bf16*)(ws + OFF_K);
  bf16*  vT     = (bf16*)(ws + OFF_VT);
  float* slots  = (float*)(ws + OFF_SL);
  bf16*  slotspb= (bf16*)(ws + OFF_SLPB);
  float* prevs  = (float*)(ws + OFF_PRV);
  bf16*  lnb    = (bf16*)(ws + OFF_LNB);
  bf16*  qb     = (bf16*)(ws + OFF_QB);
  bf16*  updb   = (bf16*)(ws + OFF_UPDB);
  bf16*  hidb   = (bf16*)(ws + OFF_HIDB);
  float* an     = (float*)(ws + OFF_AN);
  float* bn     = (float*)(ws + OFF_BN);
  float* colsum = (float*)(ws + OFF_CS);

  transpose_w<<<dim3(32,  8), 256, 0, stream>>>(W_enc, Wenc_t, DIN, DD);
  transpose_w<<<dim3(32, 32), 256, 0, stream>>>(Wk,    Wk_t,   DD,  DD);
  transpose_w<<<dim3(32, 32), 256, 0, stream>>>(Wv,    Wv_t,   DD,  DD);
  transpose_w<<<dim3(32, 32), 256, 0, stream>>>(Wq,    Wq_t,   DD,  DD);
  transpose_w<<<dim3(64, 32), 256, 0, stream>>>(W1,    W1_t,   DD,  HH);
  transpose_w<<<dim3(32, 64), 256, 0, stream>>>(W2,    W2_t,   HH,  DD);
  f32_to_bf16_v<<<(TD*DD)/1024, 256, 0, stream>>>(Wi, Wi_b, TD*DD);
  f32_to_bf16_v<<<(TD*DD)/1024, 256, 0, stream>>>(Wh, Wh_b, TD*DD);

  auto frame = [&](const float* dets, bool first) {
    f32_to_bf16_v<<<(N_DET*DIN)/1024, 256, 0, stream>>>(dets, dets_bf, N_DET*DIN);
    gemm_mfma_bt<bf16, false><<<1024, 256, 0, stream>>>(dets_bf, Wenc_t, b_enc, x_pre, N_DET, DD, DIN);
    ln_rows<bf16><<<N_DET, 256, 0, stream>>>(x_pre, x);
    gemm_mfma_bt<bf16, false><<<1024, 256, 0, stream>>>(x, Wk_t, bk, kbuf, N_DET, DD, DD);
    gemm_mfma_bt<bf16, true ><<<1024, 256, 0, stream>>>(x, Wv_t, bv, vT,   N_DET, DD, DD);
    if (first) slots_init_ln<<<64, 256, 0, stream>>>(slots_mu, init_noise, slots, slotspb, lnb);
    else       prep_ln<<<64, 256, 0, stream>>>(slots, slotspb, lnb);
    for (int it = 0; it < 3; ++it) {
      gemm_skinny_loop<<<dim3(16, 8), 256, 0, stream>>>(lnb, Wq_t, pA, DD, DD, 128);
      reduce_q<<<dim3(4, 64), 256, 0, stream>>>(pA, bq, qb, colsum);
      qk_softmax<<<256, 256, 0, stream>>>(qb, kbuf, attn, colsum);
      gemm_skinny_loop<<<dim3(16, 8), 256, 0, stream>>>(attn, vT, pA, DD, N_DET, 2048);
      updates_reduce2<8><<<dim3(4, 64), 256, 0, stream>>>(pA, colsum, updb);
      gemm_skinny_dual<<<dim3(48, 8, 2), 256, 0, stream>>>(updb, slotspb, Wi_b, Wh_b, pA, pB, TD, DD, 128);
      gru_reduce_ln<<<64, 256, 0, stream>>>(pA, pB, bi, bh, slots, lnb);
      gemm_skinny_loop<<<dim3(32, 8), 256, 0, stream>>>(lnb, W1_t, pA, HH, DD, 128);
      skinny_reduce<8, 1><<<dim3(8, 64), 256, 0, stream>>>(pA, b1, nullptr, nullptr, hidb, HH);
      gemm_skinny_loop<<<dim3(16, 16), 256, 0, stream>>>(hidb, W2_t, pA, DD, HH, 128);
      mlp2_reduce_ln<<<64, 256, 0, stream>>>(pA, b2, slots, slotspb, lnb);
    }
  };

  frame(dets_t, true);
  hipMemcpyAsync(prevs, slots, 262144, hipMemcpyDeviceToDevice, stream);
  frame(dets_t1, false);

  rownorm<<<KSLOT, 256, 0, stream>>>(prevs, an);
  rownorm<<<KSLOT, 256, 0, stream>>>(slots, bn);
  float* outf = (float*)d_out;
  sim_kernel<<<KSLOT, 256, 0, stream>>>(an, bn, outf + 64);
  match_kernel<<<1, 64, 0, stream>>>(outf + 64, outf);
}